// Round 13
// baseline (212.310 us; speedup 1.0000x reference)
//
#include <hip/hip_runtime.h>

// Problem constants
#define B_    512
#define D_TRF 5120
#define P_    32
#define E_    160
#define D_OUT 3000
#define PAD_  61
#define D_CL  4998
#define INV_SCALE 0.07905694150420949f   // 1/sqrt(160)
#define N_PAD 3072          // lin_w rows padded (32 tiles of 96)

typedef __attribute__((ext_vector_type(4))) float floatx4;
typedef __attribute__((ext_vector_type(16))) float floatx16;
typedef __attribute__((ext_vector_type(8))) short short8;

static __device__ __forceinline__ unsigned short f2bf(float f) {
    unsigned int u = __float_as_uint(f);
    unsigned int r = (u + 0x7fffu + ((u >> 16) & 1u)) >> 16;
    return (unsigned short)r;
}
static __device__ __forceinline__ float bf2f(unsigned short u) {
    return __uint_as_float(((unsigned int)u) << 16);
}
static __device__ __forceinline__ void load_lds16(const void* g, void* lds) {
    __builtin_amdgcn_global_load_lds(
        (const __attribute__((address_space(1))) unsigned int*)g,
        (__attribute__((address_space(3))) unsigned int*)lds, 16, 0, 0);
}

// ---------------------------------------------------------------------------
// K0 v2 (kept): lin_w cast + small casts, one launch (homogeneous BW work).
// ---------------------------------------------------------------------------
__global__ __launch_bounds__(256) void k_castw2(const float* __restrict__ w,
                                                unsigned short* __restrict__ wb,
                                                const float* __restrict__ wq,
                                                const float* __restrict__ wk,
                                                const float* __restrict__ wv,
                                                const float* __restrict__ btw,
                                                unsigned short* __restrict__ wqb,
                                                unsigned short* __restrict__ wkb,
                                                unsigned short* __restrict__ wvb,
                                                unsigned short* __restrict__ wtb) {
    int blk = blockIdx.x, tid = threadIdx.x;
    if (blk < 15360) {
        size_t i4 = ((size_t)blk * 256 + tid) * 4;
        size_t o = i4 / D_TRF;
        ushort4 s;
        if (o < D_OUT) {
            float4 v = *(const float4*)(w + i4);
            s.x = f2bf(v.x); s.y = f2bf(v.y); s.z = f2bf(v.z); s.w = f2bf(v.w);
        } else {
            s.x = s.y = s.z = s.w = 0;
        }
        *(ushort4*)(wb + i4) = s;
    } else {
        int idx = (blk - 15360) * 256 + tid;   // < 25600
        wqb[idx] = f2bf(wq[idx]);
        wkb[idx] = f2bf(wk[idx]);
        wvb[idx] = f2bf(wv[idx]);
        int f = idx / E_, e = idx - f * E_;
        wtb[idx] = f2bf(btw[(size_t)e * E_ + f]);
    }
}

// ---------------------------------------------------------------------------
// K_INIT: out = lin_b*g + ob (the affine base the atomic epilogue adds onto).
// 512 rows x 750 float4 = 384000 threads.
// ---------------------------------------------------------------------------
__global__ __launch_bounds__(256) void k_init(const float* __restrict__ lin_b,
                                              const float* __restrict__ out_gain,
                                              const float* __restrict__ out_bias,
                                              float* __restrict__ out) {
    int idx = blockIdx.x * 256 + threadIdx.x;   // < 384000
    int row = idx / 750, c4 = idx - row * 750;
    float4 lb = *(const float4*)(lin_b + c4 * 4);
    float g = out_gain[0], ob = out_bias[0];
    float4 o;
    o.x = lb.x * g + ob;
    o.y = lb.y * g + ob;
    o.z = lb.z * g + ob;
    o.w = lb.w * g + ob;
    *(float4*)(out + (size_t)row * D_OUT + c4 * 4) = o;
}

// ---------------------------------------------------------------------------
// K1 v3 (unchanged, verified): cl = (x*std+mean) @ mat via MFMA bf16x3.
// ---------------------------------------------------------------------------
__global__ __launch_bounds__(256) void k_cl3(const float* __restrict__ x,
                                             const float* __restrict__ stdv,
                                             const float* __restrict__ meanv,
                                             const float* __restrict__ mat,
                                             float* __restrict__ cl) {
    __shared__ __align__(16) float t[32 * 64];   // 8 KB, XOR-swizzled chunks
    int bx = blockIdx.x, by = blockIdx.y;
    int tid = threadIdx.x, wid = tid >> 6, lane = tid & 63;
    int l32 = lane & 31, hi = lane >> 5;

    #pragma unroll
    for (int s = 0; s < 2; ++s) {
        int u = s * 256 + tid;            // chunk id, 512 total
        int row = u >> 4, c = u & 15;
        int k = c * 4;
        float4 xv = *(const float4*)(x + (size_t)(bx * 32 + row) * 64 + k);
        float4 sv = *(const float4*)(stdv + k);
        float4 mv = *(const float4*)(meanv + k);
        float4 tv;
        tv.x = xv.x * sv.x + mv.x;
        tv.y = xv.y * sv.y + mv.y;
        tv.z = xv.z * sv.z + mv.z;
        tv.w = xv.w * sv.w + mv.w;
        *(float4*)(t + row * 64 + ((c ^ (row & 7)) << 2)) = tv;
    }

    if (by == 0) {
        for (int idx = tid; idx < 32 * PAD_; idx += 256) {
            int row = idx / PAD_, jj = idx - row * PAD_;
            size_t base = (size_t)(bx * 32 + row) * D_TRF;
            cl[base + jj] = 0.f;
            cl[base + (D_TRF - PAD_) + jj] = 0.f;
        }
    }
    __syncthreads();

    int j = by * 128 + wid * 32 + l32;
    bool jok = j < D_CL;

    floatx16 acc = {0.f, 0.f, 0.f, 0.f, 0.f, 0.f, 0.f, 0.f,
                    0.f, 0.f, 0.f, 0.f, 0.f, 0.f, 0.f, 0.f};
    #pragma unroll
    for (int e0i = 0; e0i < 4; ++e0i) {
        int e0 = e0i * 16;
        int c0 = (e0 >> 2) + hi * 2;
        float4 a0 = *(const float4*)(t + l32 * 64 + ((c0 ^ (l32 & 7)) << 2));
        float4 a1 = *(const float4*)(t + l32 * 64 + (((c0 + 1) ^ (l32 & 7)) << 2));
        float av[8] = {a0.x, a0.y, a0.z, a0.w, a1.x, a1.y, a1.z, a1.w};
        short8 ahi, alo;
        #pragma unroll
        for (int q = 0; q < 8; ++q) {
            unsigned short h = f2bf(av[q]);
            ahi[q] = (short)h;
            alo[q] = (short)f2bf(av[q] - bf2f(h));
        }
        float bv[8];
        #pragma unroll
        for (int kk = 0; kk < 8; ++kk) {
            int k = e0 + hi * 8 + kk;
            bv[kk] = jok ? mat[(size_t)k * D_CL + j] : 0.f;
        }
        short8 bhi, blo;
        #pragma unroll
        for (int q = 0; q < 8; ++q) {
            unsigned short h = f2bf(bv[q]);
            bhi[q] = (short)h;
            blo[q] = (short)f2bf(bv[q] - bf2f(h));
        }
        acc = __builtin_amdgcn_mfma_f32_32x32x16_bf16(ahi, bhi, acc, 0, 0, 0);
        acc = __builtin_amdgcn_mfma_f32_32x32x16_bf16(ahi, blo, acc, 0, 0, 0);
        acc = __builtin_amdgcn_mfma_f32_32x32x16_bf16(alo, bhi, acc, 0, 0, 0);
    }

    if (jok) {
        #pragma unroll
        for (int r = 0; r < 16; ++r) {
            int p = (r & 3) + 8 * (r >> 2) + 4 * hi;
            cl[(size_t)(bx * 32 + p) * D_TRF + PAD_ + j] = acc[r];
        }
    }
}

// ---------------------------------------------------------------------------
// K3456 v3 (unchanged, verified): fused LN + QKV + attention + BT,
// one block per b, 8 waves. LDS 68096 B -> 2 blocks/CU.
// ---------------------------------------------------------------------------
__global__ __launch_bounds__(512) void k_qab(const float* __restrict__ cl,
                                             const float* __restrict__ ln_g,
                                             const float* __restrict__ ln_b,
                                             const unsigned short* __restrict__ wqb,
                                             const unsigned short* __restrict__ wkb,
                                             const unsigned short* __restrict__ wvb,
                                             const unsigned short* __restrict__ wtb,
                                             const float* __restrict__ bq,
                                             const float* __restrict__ bk,
                                             const float* __restrict__ bv,
                                             const float* __restrict__ bt_b,
                                             const float* __restrict__ bt_gain,
                                             const float* __restrict__ bt_bias,
                                             const float* __restrict__ sup_g,
                                             const float* __restrict__ sup_b,
                                             unsigned short* __restrict__ yb) {
    __shared__ __align__(16) char smem[68096];
    float*          clh  = (float*)smem;                              // [32][160] cl -> h
    unsigned short* Qlds = (unsigned short*)(smem + 20480);           // [32][168]
    unsigned short* Klds = Qlds + 32 * 168;                           // [32][168]
    unsigned short* Vtl  = (unsigned short*)(smem + 41984);           // [160][40]
    unsigned short* Satt = (unsigned short*)(smem + 54784);           // [32][40]
    unsigned short* xnl  = (unsigned short*)(smem + 57344);           // [32][168] -> x2

    int b = blockIdx.x;
    int tid = threadIdx.x, wid = tid >> 6, lane = tid & 63;
    int l32 = lane & 31, hi = lane >> 5;

    const float* clg = cl + (size_t)b * D_TRF;
    #pragma unroll
    for (int it = 0; it < 3; ++it) {
        int u = it * 512 + tid;
        if (u < 1280)
            load_lds16(clg + u * 4, (char*)clh + (size_t)u * 16);
    }
    __syncthreads();   // drains vmcnt: cl staged

    {
        float s = 0.f, s2 = 0.f;
        #pragma unroll
        for (int it = 0; it < 10; ++it) {
            float v = clh[it * 512 + tid];
            s += v; s2 += v * v;
        }
        #pragma unroll
        for (int off = 32; off; off >>= 1) {
            s  += __shfl_down(s, off);
            s2 += __shfl_down(s2, off);
        }
        float* red = (float*)Qlds;   // scratch before Q is written
        if (lane == 0) { red[wid] = s; red[8 + wid] = s2; }
        __syncthreads();
        if (tid == 0) {
            float S = 0.f, S2 = 0.f;
            #pragma unroll
            for (int i = 0; i < 8; ++i) { S += red[i]; S2 += red[8 + i]; }
            float mu = S / (float)D_TRF;
            float var = S2 / (float)D_TRF - mu * mu;
            red[16] = mu; red[17] = rsqrtf(var + 1e-5f);
        }
        __syncthreads();
        float mu = red[16], rs = red[17];
        #pragma unroll
        for (int it = 0; it < 10; ++it) {
            int idx = it * 512 + tid;
            int p = idx / 160, e = idx - p * 160;
            xnl[p * 168 + e] = f2bf((clh[idx] - mu) * rs * ln_g[idx] + ln_b[idx]);
        }
    }
    __syncthreads();   // xnl ready; Qlds scratch reads done

    for (int tc = wid; tc < 15; tc += 8) {
        int mat = tc / 5, f0 = (tc - mat * 5) * 32;
        const unsigned short* wsrc = (mat == 0) ? wqb : (mat == 1) ? wkb : wvb;
        const float* bias          = (mat == 0) ? bq  : (mat == 1) ? bk  : bv;
        floatx16 acc = {0.f, 0.f, 0.f, 0.f, 0.f, 0.f, 0.f, 0.f,
                        0.f, 0.f, 0.f, 0.f, 0.f, 0.f, 0.f, 0.f};
        #pragma unroll
        for (int kc = 0; kc < 10; ++kc) {
            int e0 = kc * 16;
            short8 af = *(const short8*)(xnl + l32 * 168 + e0 + hi * 8);
            short8 bf = *(const short8*)(wsrc + (size_t)(f0 + l32) * E_ + e0 + hi * 8);
            acc = __builtin_amdgcn_mfma_f32_32x32x16_bf16(af, bf, acc, 0, 0, 0);
        }
        int f = f0 + l32;
        float bb = bias[f];
        if (mat == 0) {
            #pragma unroll
            for (int r = 0; r < 16; ++r) {
                int p = (r & 3) + 8 * (r >> 2) + 4 * hi;
                Qlds[p * 168 + f] = f2bf(acc[r] + bb);
            }
        } else if (mat == 1) {
            #pragma unroll
            for (int r = 0; r < 16; ++r) {
                int p = (r & 3) + 8 * (r >> 2) + 4 * hi;
                Klds[p * 168 + f] = f2bf(acc[r] + bb);
            }
        } else {
            #pragma unroll
            for (int r = 0; r < 16; ++r) {
                int p = (r & 3) + 8 * (r >> 2) + 4 * hi;
                Vtl[f * 40 + p] = f2bf(acc[r] + bb);   // transposed: [e][q]
            }
        }
    }
    __syncthreads();

    if (wid == 0) {
        floatx16 S = {0.f, 0.f, 0.f, 0.f, 0.f, 0.f, 0.f, 0.f,
                      0.f, 0.f, 0.f, 0.f, 0.f, 0.f, 0.f, 0.f};
        #pragma unroll
        for (int kc = 0; kc < 10; ++kc) {
            int e0 = kc * 16;
            short8 aq = *(const short8*)(Qlds + l32 * 168 + e0 + hi * 8);
            short8 bk2 = *(const short8*)(Klds + l32 * 168 + e0 + hi * 8);
            S = __builtin_amdgcn_mfma_f32_32x32x16_bf16(aq, bk2, S, 0, 0, 0);
        }
        float mx = -1e30f;
        #pragma unroll
        for (int r = 0; r < 16; ++r) { S[r] *= INV_SCALE; mx = fmaxf(mx, S[r]); }
        mx = fmaxf(mx, __shfl_xor(mx, 32));
        float ex[16];
        float sum = 0.f;
        #pragma unroll
        for (int r = 0; r < 16; ++r) { ex[r] = __expf(S[r] - mx); sum += ex[r]; }
        sum += __shfl_xor(sum, 32);
        float inv = 1.f / sum;
        #pragma unroll
        for (int r = 0; r < 16; ++r) {
            int p = (r & 3) + 8 * (r >> 2) + 4 * hi;
            Satt[p * 40 + l32] = f2bf(ex[r] * inv);
        }
    }
    __syncthreads();   // att ready; Q/K dead

    short8 a0 = *(const short8*)(Satt + l32 * 40 + hi * 8);
    short8 a1 = *(const short8*)(Satt + l32 * 40 + 16 + hi * 8);
    float gg = bt_gain[0], bb2 = bt_bias[0];
    if (wid < 5) {
        int e0 = wid * 32;
        short8 b0 = *(const short8*)(Vtl + (e0 + l32) * 40 + hi * 8);
        short8 b1 = *(const short8*)(Vtl + (e0 + l32) * 40 + 16 + hi * 8);
        floatx16 acc = {0.f, 0.f, 0.f, 0.f, 0.f, 0.f, 0.f, 0.f,
                        0.f, 0.f, 0.f, 0.f, 0.f, 0.f, 0.f, 0.f};
        acc = __builtin_amdgcn_mfma_f32_32x32x16_bf16(a0, b0, acc, 0, 0, 0);
        acc = __builtin_amdgcn_mfma_f32_32x32x16_bf16(a1, b1, acc, 0, 0, 0);
        #pragma unroll
        for (int r = 0; r < 16; ++r) {
            int p = (r & 3) + 8 * (r >> 2) + 4 * hi;
            int e = e0 + l32;
            float hv = acc[r] + clh[p * E_ + e];   // read cl, then overwrite as h
            clh[p * E_ + e] = hv;
            xnl[p * 168 + e] = f2bf(hv * gg + bb2);   // x2
        }
    }
    __syncthreads();   // h, x2 ready

    if (wid < 5) {
        int f0 = wid * 32;
        floatx16 acc = {0.f, 0.f, 0.f, 0.f, 0.f, 0.f, 0.f, 0.f,
                        0.f, 0.f, 0.f, 0.f, 0.f, 0.f, 0.f, 0.f};
        #pragma unroll
        for (int kc = 0; kc < 10; ++kc) {
            int e0 = kc * 16;
            short8 af = *(const short8*)(xnl + l32 * 168 + e0 + hi * 8);
            short8 bf = *(const short8*)(wtb + (size_t)(f0 + l32) * E_ + e0 + hi * 8);
            acc = __builtin_amdgcn_mfma_f32_32x32x16_bf16(af, bf, acc, 0, 0, 0);
        }
        int f = f0 + l32;
        float bb = bt_b[f];
        #pragma unroll
        for (int r = 0; r < 16; ++r) {
            int p = (r & 3) + 8 * (r >> 2) + 4 * hi;
            int i = p * E_ + f;
            float o = acc[r] + bb;
            float sig = 1.f / (1.f + __expf(-sup_b[i] * o));
            float y = (sup_g[i] + sig * (1.f - sup_g[i])) * o + clh[p * E_ + f];
            yb[((size_t)b * 32 + p) * E_ + f] = f2bf(y);
        }
    }
}

// ---------------------------------------------------------------------------
// K7 v13: lin10's PROVEN K-loop verbatim (27.4 us; depth-2 vmcnt(7),
// 2 blocks/CU — lin12's depth-3 @ 1 block/CU regressed to 43 us, reverted).
// Only the EPILOGUE changes: partials go straight to out via atomicAdd
// (pre-scaled by g; k_init wrote the affine base), killing k_red + the
// 25MB pb write + 25MB pb read. Cols >= 3000 (wb pad) skipped.
// ---------------------------------------------------------------------------
__global__ __launch_bounds__(256, 2) void k_lin13(const unsigned short* __restrict__ yb,
                                                  const unsigned short* __restrict__ wb,
                                                  const float* __restrict__ out_gain,
                                                  float* __restrict__ out) {
    __shared__ __align__(16) unsigned short As[2][128 * 64];  // 2 x 16 KB
    __shared__ __align__(16) unsigned short Bs[2][96 * 64];   // 2 x 12 KB

    int bid = blockIdx.x;
    int xcd = bid & 7, j = bid >> 3;
    int nt = xcd * 4 + (j & 3);          // 0..31  (96-col tiles)
    int mt = (j >> 2) & 3;               // 0..3   (128-row tiles)
    int sp = j >> 4;                     // 0..3   (split-K, 1280 each)

    int tid = threadIdx.x, wid = tid >> 6, lane = tid & 63;
    int l16 = lane & 15, quad = lane >> 4;
    int wr = wid >> 1, wc = wid & 1;     // 2x2 wave grid

    const size_t aRow0 = (size_t)(mt * 128) * D_TRF;
    const size_t bRow0 = (size_t)(nt * 96) * D_TRF;
    const int k0 = sp * 1280;

    floatx4 acc[4][3];
    #pragma unroll
    for (int fi = 0; fi < 4; ++fi)
        #pragma unroll
        for (int fj = 0; fj < 3; ++fj) acc[fi][fj] = (floatx4){0.f, 0.f, 0.f, 0.f};

    int aOff[4][2], bOff[3][2];
    #pragma unroll
    for (int fi = 0; fi < 4; ++fi) {
        int row = wr * 64 + fi * 16 + l16;
        #pragma unroll
        for (int kk = 0; kk < 2; ++kk)
            aOff[fi][kk] = row * 64 + (((quad + kk * 4) ^ (row & 7)) * 8);
    }
    #pragma unroll
    for (int fj = 0; fj < 3; ++fj) {
        int row = wc * 48 + fj * 16 + l16;
        #pragma unroll
        for (int kk = 0; kk < 2; ++kk)
            bOff[fj][kk] = row * 64 + (((quad + kk * 4) ^ (row & 7)) * 8);
    }

#define STAGE13(buf, t)                                                         \
    do {                                                                        \
        int kh_ = k0 + (t) * 64;                                                \
        _Pragma("unroll")                                                       \
        for (int i_ = 0; i_ < 4; ++i_) {                                        \
            int u_ = i_ * 256 + tid;                                            \
            int row_ = u_ >> 3, c_ = u_ & 7;                                    \
            load_lds16(yb + aRow0 + (size_t)row_ * D_TRF + kh_ +                \
                           ((c_ ^ (row_ & 7)) * 8),                             \
                       (char*)(&As[buf][0]) + (size_t)u_ * 16);                 \
        }                                                                       \
        _Pragma("unroll")                                                       \
        for (int i_ = 0; i_ < 3; ++i_) {                                        \
            int u_ = i_ * 256 + tid;                                            \
            int row_ = u_ >> 3, c_ = u_ & 7;                                    \
            load_lds16(wb + bRow0 + (size_t)row_ * D_TRF + kh_ +                \
                           ((c_ ^ (row_ & 7)) * 8),                             \
                       (char*)(&Bs[buf][0]) + (size_t)u_ * 16);                 \
        }                                                                       \
    } while (0)

    STAGE13(0, 0);                            // 7 in flight; no wait here

    for (int t = 0; t < 20; ++t) {
        int cur = t & 1;
        if (t < 19) {
            STAGE13(cur ^ 1, t + 1);          // -> 14 in flight
            asm volatile("s_waitcnt vmcnt(7)" ::: "memory");   // tile t landed
        } else {
            asm volatile("s_waitcnt vmcnt(0)" ::: "memory");   // last tile
        }
        __builtin_amdgcn_s_barrier();         // raw: does NOT drain vmcnt

        const unsigned short* Ab = &As[cur][0];
        const unsigned short* Bb = &Bs[cur][0];
        short8 af[4][2], bfr[3][2];
        #pragma unroll
        for (int fi = 0; fi < 4; ++fi)
            #pragma unroll
            for (int kk = 0; kk < 2; ++kk)
                af[fi][kk] = *(const short8*)(Ab + aOff[fi][kk]);
        #pragma unroll
        for (int fj = 0; fj < 3; ++fj)
            #pragma unroll
            for (int kk = 0; kk < 2; ++kk)
                bfr[fj][kk] = *(const short8*)(Bb + bOff[fj][kk]);

        #pragma unroll
        for (int kk = 0; kk < 2; ++kk)
            #pragma unroll
            for (int fi = 0; fi < 4; ++fi)
                #pragma unroll
                for (int fj = 0; fj < 3; ++fj)
                    acc[fi][fj] = __builtin_amdgcn_mfma_f32_16x16x32_bf16(
                        af[fi][kk], bfr[fj][kk], acc[fi][fj], 0, 0, 0);

        asm volatile("s_waitcnt lgkmcnt(0)" ::: "memory");  // all ds_reads done
        __builtin_amdgcn_s_barrier();         // guards buf overwrite next iter
    }
#undef STAGE13

    // epilogue: atomic accumulate into out (k_init wrote lin_b*g + ob)
    float g = out_gain[0];
    #pragma unroll
    for (int fi = 0; fi < 4; ++fi) {
        int row = mt * 128 + wr * 64 + fi * 16 + quad * 4;
        #pragma unroll
        for (int fj = 0; fj < 3; ++fj) {
            int col = nt * 96 + wc * 48 + fj * 16 + l16;
            if (col < D_OUT) {
                #pragma unroll
                for (int r = 0; r < 4; ++r)
                    atomicAdd(&out[(size_t)(row + r) * D_OUT + col],
                              acc[fi][fj][r] * g);
            }
        }
    }
}

// ---------------------------------------------------------------------------
// Workspace layout (bytes)
// ---------------------------------------------------------------------------
#define SZ_ROWF ((size_t)B_ * D_TRF * 4)           // 10,485,760
#define SZ_ROWB ((size_t)B_ * D_TRF * 2)           // 5,242,880
#define OFF_CL  ((size_t)0)
#define OFF_YB  (OFF_CL + 2 * SZ_ROWF + 4 * SZ_ROWB)   // 41,943,040
#define OFF_WSM (OFF_YB + SZ_ROWB)                 // 4 x 51200 B
#define OFF_WB  (OFF_WSM + (size_t)4 * E_ * E_ * 2)
// end = OFF_WB + 3072*5120*2 = 78,848,000 bytes

extern "C" void kernel_launch(void* const* d_in, const int* in_sizes, int n_in,
                              void* d_out, int out_size, void* d_ws, size_t ws_size,
                              hipStream_t stream) {
    const float* x        = (const float*)d_in[0];
    const float* stdv     = (const float*)d_in[1];
    const float* meanv    = (const float*)d_in[2];
    const float* mat      = (const float*)d_in[3];
    const float* ln_g     = (const float*)d_in[4];
    const float* ln_b     = (const float*)d_in[5];
    const float* wq       = (const float*)d_in[6];
    const float* bq       = (const float*)d_in[7];
    const float* wk       = (const float*)d_in[8];
    const float* bk       = (const float*)d_in[9];
    const float* wv       = (const float*)d_in[10];
    const float* bv       = (const float*)d_in[11];
    const float* bt_w     = (const float*)d_in[12];
    const float* bt_b     = (const float*)d_in[13];
    const float* bt_gain  = (const float*)d_in[14];
    const float* bt_bias  = (const float*)d_in[15];
    const float* sup_g    = (const float*)d_in[16];
    const float* sup_b    = (const float*)d_in[17];
    const float* lin_w    = (const float*)d_in[18];
    const float* lin_b    = (const float*)d_in[19];
    const float* out_gain = (const float*)d_in[20];
    const float* out_bias = (const float*)d_in[21];

    char* ws = (char*)d_ws;
    float* cl = (float*)(ws + OFF_CL);
    unsigned short* yb  = (unsigned short*)(ws + OFF_YB);
    unsigned short* wqb = (unsigned short*)(ws + OFF_WSM);
    unsigned short* wkb = wqb + E_ * E_;
    unsigned short* wvb = wkb + E_ * E_;
    unsigned short* wtb = wvb + E_ * E_;
    unsigned short* wb  = (unsigned short*)(ws + OFF_WB);
    float* out = (float*)d_out;

    k_castw2<<<15460, 256, 0, stream>>>(lin_w, wb, wq, wk, wv, bt_w,
                                        wqb, wkb, wvb, wtb);
    k_init<<<1500, 256, 0, stream>>>(lin_b, out_gain, out_bias, out);
    k_cl3<<<dim3(16, 40), 256, 0, stream>>>(x, stdv, meanv, mat, cl);
    k_qab<<<512, 512, 0, stream>>>(cl, ln_g, ln_b, wqb, wkb, wvb, wtb,
                                   bq, bk, bv, bt_b, bt_gain, bt_bias,
                                   sup_g, sup_b, yb);
    k_lin13<<<512, 256, 0, stream>>>(yb, wb, out_gain, out);
}

// Round 14
// 199.870 us; speedup vs baseline: 1.0622x; 1.0622x over previous
//
#include <hip/hip_runtime.h>

// Problem constants
#define B_    512
#define D_TRF 5120
#define P_    32
#define E_    160
#define D_OUT 3000
#define PAD_  61
#define D_CL  4998
#define INV_SCALE 0.07905694150420949f   // 1/sqrt(160)
#define N_PAD 3072          // head-GEMM cols padded (32 tiles of 96)

typedef __attribute__((ext_vector_type(4))) float floatx4;
typedef __attribute__((ext_vector_type(16))) float floatx16;
typedef __attribute__((ext_vector_type(8))) short short8;

static __device__ __forceinline__ unsigned short f2bf(float f) {
    unsigned int u = __float_as_uint(f);
    unsigned int r = (u + 0x7fffu + ((u >> 16) & 1u)) >> 16;
    return (unsigned short)r;
}
static __device__ __forceinline__ float bf2f(unsigned short u) {
    return __uint_as_float(((unsigned int)u) << 16);
}
static __device__ __forceinline__ void load_lds16(const void* g, void* lds) {
    __builtin_amdgcn_global_load_lds(
        (const __attribute__((address_space(1))) unsigned int*)g,
        (__attribute__((address_space(3))) unsigned int*)lds, 16, 0, 0);
}

// ---------------------------------------------------------------------------
// K0b: cast wq/wk/wv to bf16; transpose bt_w -> wtb[f][e] = bt_w[e][f].
// (lin_w cast kernel DELETED: k_lin14 stages B as f32 and converts in-loop.)
// ---------------------------------------------------------------------------
__global__ __launch_bounds__(256) void k_cast_small(const float* __restrict__ wq,
                                                    const float* __restrict__ wk,
                                                    const float* __restrict__ wv,
                                                    const float* __restrict__ btw,
                                                    unsigned short* __restrict__ wqb,
                                                    unsigned short* __restrict__ wkb,
                                                    unsigned short* __restrict__ wvb,
                                                    unsigned short* __restrict__ wtb) {
    int idx = blockIdx.x * 256 + threadIdx.x;   // < 25600
    wqb[idx] = f2bf(wq[idx]);
    wkb[idx] = f2bf(wk[idx]);
    wvb[idx] = f2bf(wv[idx]);
    int f = idx / E_, e = idx - f * E_;
    wtb[idx] = f2bf(btw[(size_t)e * E_ + f]);
}

// ---------------------------------------------------------------------------
// K1 v3 (unchanged, verified): cl = (x*std+mean) @ mat via MFMA bf16x3.
// ---------------------------------------------------------------------------
__global__ __launch_bounds__(256) void k_cl3(const float* __restrict__ x,
                                             const float* __restrict__ stdv,
                                             const float* __restrict__ meanv,
                                             const float* __restrict__ mat,
                                             float* __restrict__ cl) {
    __shared__ __align__(16) float t[32 * 64];   // 8 KB, XOR-swizzled chunks
    int bx = blockIdx.x, by = blockIdx.y;
    int tid = threadIdx.x, wid = tid >> 6, lane = tid & 63;
    int l32 = lane & 31, hi = lane >> 5;

    #pragma unroll
    for (int s = 0; s < 2; ++s) {
        int u = s * 256 + tid;            // chunk id, 512 total
        int row = u >> 4, c = u & 15;
        int k = c * 4;
        float4 xv = *(const float4*)(x + (size_t)(bx * 32 + row) * 64 + k);
        float4 sv = *(const float4*)(stdv + k);
        float4 mv = *(const float4*)(meanv + k);
        float4 tv;
        tv.x = xv.x * sv.x + mv.x;
        tv.y = xv.y * sv.y + mv.y;
        tv.z = xv.z * sv.z + mv.z;
        tv.w = xv.w * sv.w + mv.w;
        *(float4*)(t + row * 64 + ((c ^ (row & 7)) << 2)) = tv;
    }

    if (by == 0) {
        for (int idx = tid; idx < 32 * PAD_; idx += 256) {
            int row = idx / PAD_, jj = idx - row * PAD_;
            size_t base = (size_t)(bx * 32 + row) * D_TRF;
            cl[base + jj] = 0.f;
            cl[base + (D_TRF - PAD_) + jj] = 0.f;
        }
    }
    __syncthreads();

    int j = by * 128 + wid * 32 + l32;
    bool jok = j < D_CL;

    floatx16 acc = {0.f, 0.f, 0.f, 0.f, 0.f, 0.f, 0.f, 0.f,
                    0.f, 0.f, 0.f, 0.f, 0.f, 0.f, 0.f, 0.f};
    #pragma unroll
    for (int e0i = 0; e0i < 4; ++e0i) {
        int e0 = e0i * 16;
        int c0 = (e0 >> 2) + hi * 2;
        float4 a0 = *(const float4*)(t + l32 * 64 + ((c0 ^ (l32 & 7)) << 2));
        float4 a1 = *(const float4*)(t + l32 * 64 + (((c0 + 1) ^ (l32 & 7)) << 2));
        float av[8] = {a0.x, a0.y, a0.z, a0.w, a1.x, a1.y, a1.z, a1.w};
        short8 ahi, alo;
        #pragma unroll
        for (int q = 0; q < 8; ++q) {
            unsigned short h = f2bf(av[q]);
            ahi[q] = (short)h;
            alo[q] = (short)f2bf(av[q] - bf2f(h));
        }
        float bv[8];
        #pragma unroll
        for (int kk = 0; kk < 8; ++kk) {
            int k = e0 + hi * 8 + kk;
            bv[kk] = jok ? mat[(size_t)k * D_CL + j] : 0.f;
        }
        short8 bhi, blo;
        #pragma unroll
        for (int q = 0; q < 8; ++q) {
            unsigned short h = f2bf(bv[q]);
            bhi[q] = (short)h;
            blo[q] = (short)f2bf(bv[q] - bf2f(h));
        }
        acc = __builtin_amdgcn_mfma_f32_32x32x16_bf16(ahi, bhi, acc, 0, 0, 0);
        acc = __builtin_amdgcn_mfma_f32_32x32x16_bf16(ahi, blo, acc, 0, 0, 0);
        acc = __builtin_amdgcn_mfma_f32_32x32x16_bf16(alo, bhi, acc, 0, 0, 0);
    }

    if (jok) {
        #pragma unroll
        for (int r = 0; r < 16; ++r) {
            int p = (r & 3) + 8 * (r >> 2) + 4 * hi;
            cl[(size_t)(bx * 32 + p) * D_TRF + PAD_ + j] = acc[r];
        }
    }
}

// ---------------------------------------------------------------------------
// K3456 v3 (unchanged, verified): fused LN + QKV + attention + BT,
// one block per b, 8 waves. LDS 68096 B -> 2 blocks/CU.
// ---------------------------------------------------------------------------
__global__ __launch_bounds__(512) void k_qab(const float* __restrict__ cl,
                                             const float* __restrict__ ln_g,
                                             const float* __restrict__ ln_b,
                                             const unsigned short* __restrict__ wqb,
                                             const unsigned short* __restrict__ wkb,
                                             const unsigned short* __restrict__ wvb,
                                             const unsigned short* __restrict__ wtb,
                                             const float* __restrict__ bq,
                                             const float* __restrict__ bk,
                                             const float* __restrict__ bv,
                                             const float* __restrict__ bt_b,
                                             const float* __restrict__ bt_gain,
                                             const float* __restrict__ bt_bias,
                                             const float* __restrict__ sup_g,
                                             const float* __restrict__ sup_b,
                                             unsigned short* __restrict__ yb) {
    __shared__ __align__(16) char smem[68096];
    float*          clh  = (float*)smem;                              // [32][160] cl -> h
    unsigned short* Qlds = (unsigned short*)(smem + 20480);           // [32][168]
    unsigned short* Klds = Qlds + 32 * 168;                           // [32][168]
    unsigned short* Vtl  = (unsigned short*)(smem + 41984);           // [160][40]
    unsigned short* Satt = (unsigned short*)(smem + 54784);           // [32][40]
    unsigned short* xnl  = (unsigned short*)(smem + 57344);           // [32][168] -> x2

    int b = blockIdx.x;
    int tid = threadIdx.x, wid = tid >> 6, lane = tid & 63;
    int l32 = lane & 31, hi = lane >> 5;

    const float* clg = cl + (size_t)b * D_TRF;
    #pragma unroll
    for (int it = 0; it < 3; ++it) {
        int u = it * 512 + tid;
        if (u < 1280)
            load_lds16(clg + u * 4, (char*)clh + (size_t)u * 16);
    }
    __syncthreads();   // drains vmcnt: cl staged

    {
        float s = 0.f, s2 = 0.f;
        #pragma unroll
        for (int it = 0; it < 10; ++it) {
            float v = clh[it * 512 + tid];
            s += v; s2 += v * v;
        }
        #pragma unroll
        for (int off = 32; off; off >>= 1) {
            s  += __shfl_down(s, off);
            s2 += __shfl_down(s2, off);
        }
        float* red = (float*)Qlds;   // scratch before Q is written
        if (lane == 0) { red[wid] = s; red[8 + wid] = s2; }
        __syncthreads();
        if (tid == 0) {
            float S = 0.f, S2 = 0.f;
            #pragma unroll
            for (int i = 0; i < 8; ++i) { S += red[i]; S2 += red[8 + i]; }
            float mu = S / (float)D_TRF;
            float var = S2 / (float)D_TRF - mu * mu;
            red[16] = mu; red[17] = rsqrtf(var + 1e-5f);
        }
        __syncthreads();
        float mu = red[16], rs = red[17];
        #pragma unroll
        for (int it = 0; it < 10; ++it) {
            int idx = it * 512 + tid;
            int p = idx / 160, e = idx - p * 160;
            xnl[p * 168 + e] = f2bf((clh[idx] - mu) * rs * ln_g[idx] + ln_b[idx]);
        }
    }
    __syncthreads();   // xnl ready; Qlds scratch reads done

    for (int tc = wid; tc < 15; tc += 8) {
        int mat = tc / 5, f0 = (tc - mat * 5) * 32;
        const unsigned short* wsrc = (mat == 0) ? wqb : (mat == 1) ? wkb : wvb;
        const float* bias          = (mat == 0) ? bq  : (mat == 1) ? bk  : bv;
        floatx16 acc = {0.f, 0.f, 0.f, 0.f, 0.f, 0.f, 0.f, 0.f,
                        0.f, 0.f, 0.f, 0.f, 0.f, 0.f, 0.f, 0.f};
        #pragma unroll
        for (int kc = 0; kc < 10; ++kc) {
            int e0 = kc * 16;
            short8 af = *(const short8*)(xnl + l32 * 168 + e0 + hi * 8);
            short8 bf = *(const short8*)(wsrc + (size_t)(f0 + l32) * E_ + e0 + hi * 8);
            acc = __builtin_amdgcn_mfma_f32_32x32x16_bf16(af, bf, acc, 0, 0, 0);
        }
        int f = f0 + l32;
        float bb = bias[f];
        if (mat == 0) {
            #pragma unroll
            for (int r = 0; r < 16; ++r) {
                int p = (r & 3) + 8 * (r >> 2) + 4 * hi;
                Qlds[p * 168 + f] = f2bf(acc[r] + bb);
            }
        } else if (mat == 1) {
            #pragma unroll
            for (int r = 0; r < 16; ++r) {
                int p = (r & 3) + 8 * (r >> 2) + 4 * hi;
                Klds[p * 168 + f] = f2bf(acc[r] + bb);
            }
        } else {
            #pragma unroll
            for (int r = 0; r < 16; ++r) {
                int p = (r & 3) + 8 * (r >> 2) + 4 * hi;
                Vtl[f * 40 + p] = f2bf(acc[r] + bb);   // transposed: [e][q]
            }
        }
    }
    __syncthreads();

    if (wid == 0) {
        floatx16 S = {0.f, 0.f, 0.f, 0.f, 0.f, 0.f, 0.f, 0.f,
                      0.f, 0.f, 0.f, 0.f, 0.f, 0.f, 0.f, 0.f};
        #pragma unroll
        for (int kc = 0; kc < 10; ++kc) {
            int e0 = kc * 16;
            short8 aq = *(const short8*)(Qlds + l32 * 168 + e0 + hi * 8);
            short8 bk2 = *(const short8*)(Klds + l32 * 168 + e0 + hi * 8);
            S = __builtin_amdgcn_mfma_f32_32x32x16_bf16(aq, bk2, S, 0, 0, 0);
        }
        float mx = -1e30f;
        #pragma unroll
        for (int r = 0; r < 16; ++r) { S[r] *= INV_SCALE; mx = fmaxf(mx, S[r]); }
        mx = fmaxf(mx, __shfl_xor(mx, 32));
        float ex[16];
        float sum = 0.f;
        #pragma unroll
        for (int r = 0; r < 16; ++r) { ex[r] = __expf(S[r] - mx); sum += ex[r]; }
        sum += __shfl_xor(sum, 32);
        float inv = 1.f / sum;
        #pragma unroll
        for (int r = 0; r < 16; ++r) {
            int p = (r & 3) + 8 * (r >> 2) + 4 * hi;
            Satt[p * 40 + l32] = f2bf(ex[r] * inv);
        }
    }
    __syncthreads();   // att ready; Q/K dead

    short8 a0 = *(const short8*)(Satt + l32 * 40 + hi * 8);
    short8 a1 = *(const short8*)(Satt + l32 * 40 + 16 + hi * 8);
    float gg = bt_gain[0], bb2 = bt_bias[0];
    if (wid < 5) {
        int e0 = wid * 32;
        short8 b0 = *(const short8*)(Vtl + (e0 + l32) * 40 + hi * 8);
        short8 b1 = *(const short8*)(Vtl + (e0 + l32) * 40 + 16 + hi * 8);
        floatx16 acc = {0.f, 0.f, 0.f, 0.f, 0.f, 0.f, 0.f, 0.f,
                        0.f, 0.f, 0.f, 0.f, 0.f, 0.f, 0.f, 0.f};
        acc = __builtin_amdgcn_mfma_f32_32x32x16_bf16(a0, b0, acc, 0, 0, 0);
        acc = __builtin_amdgcn_mfma_f32_32x32x16_bf16(a1, b1, acc, 0, 0, 0);
        #pragma unroll
        for (int r = 0; r < 16; ++r) {
            int p = (r & 3) + 8 * (r >> 2) + 4 * hi;
            int e = e0 + l32;
            float hv = acc[r] + clh[p * E_ + e];   // read cl, then overwrite as h
            clh[p * E_ + e] = hv;
            xnl[p * 168 + e] = f2bf(hv * gg + bb2);   // x2
        }
    }
    __syncthreads();   // h, x2 ready

    if (wid < 5) {
        int f0 = wid * 32;
        floatx16 acc = {0.f, 0.f, 0.f, 0.f, 0.f, 0.f, 0.f, 0.f,
                        0.f, 0.f, 0.f, 0.f, 0.f, 0.f, 0.f, 0.f};
        #pragma unroll
        for (int kc = 0; kc < 10; ++kc) {
            int e0 = kc * 16;
            short8 af = *(const short8*)(xnl + l32 * 168 + e0 + hi * 8);
            short8 bf = *(const short8*)(wtb + (size_t)(f0 + l32) * E_ + e0 + hi * 8);
            acc = __builtin_amdgcn_mfma_f32_32x32x16_bf16(af, bf, acc, 0, 0, 0);
        }
        int f = f0 + l32;
        float bb = bt_b[f];
        #pragma unroll
        for (int r = 0; r < 16; ++r) {
            int p = (r & 3) + 8 * (r >> 2) + 4 * hi;
            int i = p * E_ + f;
            float o = acc[r] + bb;
            float sig = 1.f / (1.f + __expf(-sup_b[i] * o));
            float y = (sup_g[i] + sig * (1.f - sup_g[i])) * o + clh[p * E_ + f];
            yb[((size_t)b * 32 + p) * E_ + f] = f2bf(y);
        }
    }
}

// ---------------------------------------------------------------------------
// K7 v14: lin10's PROVEN K-loop + pb epilogue (lin13's atomics regressed
// +22us -> reverted), with ONE change: B staged as F32 straight from lin_w
// via global_load_lds, converted f32->bf16 AFTER the compiler-managed
// ds_read (no loop-carried loaded regs -> avoids v11's waitcnt trap).
// Kills the lin_w cast kernel (-92MB traffic, -1 launch) for +30MB here.
// LDS: A 2x16KB bf16 + B 2x24KB f32 = 80KB -> exactly 2 blocks/CU.
// Stage = 10 vmem/wave (A:4, B:6) -> steady-state vmcnt(10) (lin10's proven
// schedule shape, count adjusted). Pad rows >=3000 clamp to row 0 (garbage
// cols 3000..3071 are never read by k_red2). Numerics: same f2bf RNE as
// the deleted castw -> absmax unchanged.
// ---------------------------------------------------------------------------
__global__ __launch_bounds__(256, 2) void k_lin14(const unsigned short* __restrict__ yb,
                                                  const float* __restrict__ w,
                                                  float* __restrict__ pb) {
    __shared__ __align__(16) unsigned short As[2][128 * 64];  // 2 x 16 KB
    __shared__ __align__(16) float Bs[2][96 * 64];            // 2 x 24 KB

    int bid = blockIdx.x;
    int xcd = bid & 7, j = bid >> 3;
    int nt = xcd * 4 + (j & 3);          // 0..31  (96-col tiles)
    int mt = (j >> 2) & 3;               // 0..3   (128-row tiles)
    int sp = j >> 4;                     // 0..3   (split-K, 1280 each)

    int tid = threadIdx.x, wid = tid >> 6, lane = tid & 63;
    int l16 = lane & 15, quad = lane >> 4;
    int wr = wid >> 1, wc = wid & 1;     // 2x2 wave grid

    const size_t aRow0 = (size_t)(mt * 128) * D_TRF;
    const int k0 = sp * 1280;

    floatx4 acc[4][3];
    #pragma unroll
    for (int fi = 0; fi < 4; ++fi)
        #pragma unroll
        for (int fj = 0; fj < 3; ++fj) acc[fi][fj] = (floatx4){0.f, 0.f, 0.f, 0.f};

    // A ds-read offsets (bf16 shorts), proven swizzle
    int aOff[4][2];
    #pragma unroll
    for (int fi = 0; fi < 4; ++fi) {
        int row = wr * 64 + fi * 16 + l16;
        #pragma unroll
        for (int kk = 0; kk < 2; ++kk)
            aOff[fi][kk] = row * 64 + (((quad + kk * 4) ^ (row & 7)) * 8);
    }
    // B ds-read offsets (f32): frag k-cols quad*8+kk*32 .. +7 = chunks
    // c0=quad*2+kk*8 and c0+1 (4 f32 each), swizzled per-chunk.
    int bOffA[3][2], bOffB[3][2];
    #pragma unroll
    for (int fj = 0; fj < 3; ++fj) {
        int row = wc * 48 + fj * 16 + l16;
        #pragma unroll
        for (int kk = 0; kk < 2; ++kk) {
            int c0 = quad * 2 + kk * 8;
            bOffA[fj][kk] = row * 64 + (((c0)     ^ (row & 7)) << 2);
            bOffB[fj][kk] = row * 64 + (((c0 + 1) ^ (row & 7)) << 2);
        }
    }

    // stage: A = 1024 bf16-chunks (4 insts/wave), B = 1536 f32-chunks
    // (6 insts/wave) -> 10 vmem/wave, uniform.
#define STAGE14(buf, t)                                                         \
    do {                                                                        \
        int kh_ = k0 + (t) * 64;                                                \
        _Pragma("unroll")                                                       \
        for (int i_ = 0; i_ < 4; ++i_) {                                        \
            int u_ = i_ * 256 + tid;                                            \
            int row_ = u_ >> 3, c_ = u_ & 7;                                    \
            load_lds16(yb + aRow0 + (size_t)row_ * D_TRF + kh_ +                \
                           ((c_ ^ (row_ & 7)) * 8),                             \
                       (char*)(&As[buf][0]) + (size_t)u_ * 16);                 \
        }                                                                       \
        _Pragma("unroll")                                                       \
        for (int i_ = 0; i_ < 6; ++i_) {                                        \
            int u_ = i_ * 256 + tid;                                            \
            int row_ = u_ >> 4, c_ = u_ & 15;                                   \
            int wr_ = nt * 96 + row_;                                           \
            if (wr_ >= D_OUT) wr_ = 0;   /* clamp: garbage cols discarded */    \
            load_lds16(w + (size_t)wr_ * D_TRF + kh_ +                          \
                           (((c_ ^ (row_ & 7)) << 2)),                          \
                       (char*)(&Bs[buf][0]) + (size_t)u_ * 16);                 \
        }                                                                       \
    } while (0)

    STAGE14(0, 0);                            // 10 in flight; no wait here

    for (int t = 0; t < 20; ++t) {
        int cur = t & 1;
        if (t < 19) {
            STAGE14(cur ^ 1, t + 1);          // -> 20 in flight
            asm volatile("s_waitcnt vmcnt(10)" ::: "memory");  // tile t landed
        } else {
            asm volatile("s_waitcnt vmcnt(0)" ::: "memory");   // last tile
        }
        __builtin_amdgcn_s_barrier();         // raw: does NOT drain vmcnt

        const unsigned short* Ab = &As[cur][0];
        const float* Bb = &Bs[cur][0];
        short8 af[4][2], bfr[3][2];
        #pragma unroll
        for (int fi = 0; fi < 4; ++fi)
            #pragma unroll
            for (int kk = 0; kk < 2; ++kk)
                af[fi][kk] = *(const short8*)(Ab + aOff[fi][kk]);
        #pragma unroll
        for (int fj = 0; fj < 3; ++fj)
            #pragma unroll
            for (int kk = 0; kk < 2; ++kk) {
                float4 b0 = *(const float4*)(Bb + bOffA[fj][kk]);
                float4 b1 = *(const float4*)(Bb + bOffB[fj][kk]);
                short8 bf;
                bf[0] = (short)f2bf(b0.x); bf[1] = (short)f2bf(b0.y);
                bf[2] = (short)f2bf(b0.z); bf[3] = (short)f2bf(b0.w);
                bf[4] = (short)f2bf(b1.x); bf[5] = (short)f2bf(b1.y);
                bf[6] = (short)f2bf(b1.z); bf[7] = (short)f2bf(b1.w);
                bfr[fj][kk] = bf;
            }

        #pragma unroll
        for (int kk = 0; kk < 2; ++kk)
            #pragma unroll
            for (int fi = 0; fi < 4; ++fi)
                #pragma unroll
                for (int fj = 0; fj < 3; ++fj)
                    acc[fi][fj] = __builtin_amdgcn_mfma_f32_16x16x32_bf16(
                        af[fi][kk], bfr[fj][kk], acc[fi][fj], 0, 0, 0);

        asm volatile("s_waitcnt lgkmcnt(0)" ::: "memory");  // all ds_reads done
        __builtin_amdgcn_s_barrier();         // guards buf overwrite next iter
    }
#undef STAGE14

    // epilogue: plain coalesced partial stores (proven path)
    #pragma unroll
    for (int fi = 0; fi < 4; ++fi) {
        int row = mt * 128 + wr * 64 + fi * 16 + quad * 4;
        #pragma unroll
        for (int fj = 0; fj < 3; ++fj) {
            int col = nt * 96 + wc * 48 + fj * 16 + l16;
            #pragma unroll
            for (int r = 0; r < 4; ++r)
                pb[((size_t)(sp * 512 + row + r)) * 3072 + col] = acc[fi][fj][r];
        }
    }
}

// ---------------------------------------------------------------------------
// K8 v2 (restored, measured fine): reduce 4 split-K partials + bias/gain,
// float4-vectorized. 512 rows x 750 col4 = 384000 threads, exact cover.
// ---------------------------------------------------------------------------
__global__ __launch_bounds__(256) void k_red2(const float* __restrict__ pb,
                                              const float* __restrict__ lin_b,
                                              const float* __restrict__ out_gain,
                                              const float* __restrict__ out_bias,
                                              float* __restrict__ out) {
    int idx = blockIdx.x * 256 + threadIdx.x;   // < 384000
    int row = idx / 750, c4 = idx - row * 750;
    size_t base = (size_t)row * 3072 + c4 * 4;
    const size_t stride = (size_t)512 * 3072;
    float4 s0 = *(const float4*)(pb + base);
    float4 s1 = *(const float4*)(pb + base + stride);
    float4 s2 = *(const float4*)(pb + base + 2 * stride);
    float4 s3 = *(const float4*)(pb + base + 3 * stride);
    float4 lb = *(const float4*)(lin_b + c4 * 4);
    float g = out_gain[0], ob = out_bias[0];
    float4 o;
    o.x = (s0.x + s1.x + s2.x + s3.x + lb.x) * g + ob;
    o.y = (s0.y + s1.y + s2.y + s3.y + lb.y) * g + ob;
    o.z = (s0.z + s1.z + s2.z + s3.z + lb.z) * g + ob;
    o.w = (s0.w + s1.w + s2.w + s3.w + lb.w) * g + ob;
    *(float4*)(out + (size_t)row * D_OUT + c4 * 4) = o;
}

// ---------------------------------------------------------------------------
// Workspace layout (bytes)
// ---------------------------------------------------------------------------
#define SZ_ROWF ((size_t)B_ * D_TRF * 4)           // 10,485,760
#define SZ_ROWB ((size_t)B_ * D_TRF * 2)           // 5,242,880
#define OFF_CL  ((size_t)0)
#define OFF_YB  (OFF_CL + 2 * SZ_ROWF + 4 * SZ_ROWB)   // 41,943,040
#define OFF_WSM (OFF_YB + SZ_ROWB)                 // 4 x 51200 B
// pb (4*512*3072*4 = 25,165,824 B) aliases OFF_CL..: cl is dead once k_qab
// has run, and 25.2 MB < OFF_YB (41.9 MB) -> yb untouched.

extern "C" void kernel_launch(void* const* d_in, const int* in_sizes, int n_in,
                              void* d_out, int out_size, void* d_ws, size_t ws_size,
                              hipStream_t stream) {
    const float* x        = (const float*)d_in[0];
    const float* stdv     = (const float*)d_in[1];
    const float* meanv    = (const float*)d_in[2];
    const float* mat      = (const float*)d_in[3];
    const float* ln_g     = (const float*)d_in[4];
    const float* ln_b     = (const float*)d_in[5];
    const float* wq       = (const float*)d_in[6];
    const float* bq       = (const float*)d_in[7];
    const float* wk       = (const float*)d_in[8];
    const float* bk       = (const float*)d_in[9];
    const float* wv       = (const float*)d_in[10];
    const float* bv       = (const float*)d_in[11];
    const float* bt_w     = (const float*)d_in[12];
    const float* bt_b     = (const float*)d_in[13];
    const float* bt_gain  = (const float*)d_in[14];
    const float* bt_bias  = (const float*)d_in[15];
    const float* sup_g    = (const float*)d_in[16];
    const float* sup_b    = (const float*)d_in[17];
    const float* lin_w    = (const float*)d_in[18];
    const float* lin_b    = (const float*)d_in[19];
    const float* out_gain = (const float*)d_in[20];
    const float* out_bias = (const float*)d_in[21];

    char* ws = (char*)d_ws;
    float* cl = (float*)(ws + OFF_CL);
    unsigned short* yb  = (unsigned short*)(ws + OFF_YB);
    unsigned short* wqb = (unsigned short*)(ws + OFF_WSM);
    unsigned short* wkb = wqb + E_ * E_;
    unsigned short* wvb = wkb + E_ * E_;
    unsigned short* wtb = wvb + E_ * E_;
    float* pb = (float*)(ws + OFF_CL);   // aliases cl (dead by k_lin14)
    float* out = (float*)d_out;

    k_cast_small<<<100, 256, 0, stream>>>(wq, wk, wv, bt_w, wqb, wkb, wvb, wtb);
    k_cl3<<<dim3(16, 40), 256, 0, stream>>>(x, stdv, meanv, mat, cl);
    k_qab<<<512, 512, 0, stream>>>(cl, ln_g, ln_b, wqb, wkb, wvb, wtb,
                                   bq, bk, bv, bt_b, bt_gain, bt_bias,
                                   sup_g, sup_b, yb);
    k_lin14<<<512, 256, 0, stream>>>(yb, lin_w, pb);
    k_red2<<<1500, 256, 0, stream>>>(pb, lin_b, out_gain, out_bias, out);
}

// Round 15
// 190.354 us; speedup vs baseline: 1.1153x; 1.0500x over previous
//
#include <hip/hip_runtime.h>

// Problem constants
#define B_    512
#define D_TRF 5120
#define P_    32
#define E_    160
#define D_OUT 3000
#define PAD_  61
#define D_CL  4998
#define INV_SCALE 0.07905694150420949f   // 1/sqrt(160)
#define N_PAD 3072          // lin_w rows padded (32 tiles of 96)

typedef __attribute__((ext_vector_type(4))) float floatx4;
typedef __attribute__((ext_vector_type(16))) float floatx16;
typedef __attribute__((ext_vector_type(8))) short short8;

static __device__ __forceinline__ unsigned short f2bf(float f) {
    unsigned int u = __float_as_uint(f);
    unsigned int r = (u + 0x7fffu + ((u >> 16) & 1u)) >> 16;
    return (unsigned short)r;
}
static __device__ __forceinline__ float bf2f(unsigned short u) {
    return __uint_as_float(((unsigned int)u) << 16);
}
static __device__ __forceinline__ void load_lds16(const void* g, void* lds) {
    __builtin_amdgcn_global_load_lds(
        (const __attribute__((address_space(1))) unsigned int*)g,
        (__attribute__((address_space(3))) unsigned int*)lds, 16, 0, 0);
}

// ---------------------------------------------------------------------------
// K0 v2: lin_w cast + small casts, one launch (homogeneous BW work).
// KEPT as separate pre-pass: three attempts to fuse the cast into the GEMM
// (v11 reg-stage, v14 f32-LDS+in-loop cvt) regressed +22us each — per-elem
// work between ds_read and MFMA costs more than a BW-bound pre-pass.
// ---------------------------------------------------------------------------
__global__ __launch_bounds__(256) void k_castw2(const float* __restrict__ w,
                                                unsigned short* __restrict__ wb,
                                                const float* __restrict__ wq,
                                                const float* __restrict__ wk,
                                                const float* __restrict__ wv,
                                                const float* __restrict__ btw,
                                                unsigned short* __restrict__ wqb,
                                                unsigned short* __restrict__ wkb,
                                                unsigned short* __restrict__ wvb,
                                                unsigned short* __restrict__ wtb) {
    int blk = blockIdx.x, tid = threadIdx.x;
    if (blk < 15360) {
        size_t i4 = ((size_t)blk * 256 + tid) * 4;
        size_t o = i4 / D_TRF;
        ushort4 s;
        if (o < D_OUT) {
            float4 v = *(const float4*)(w + i4);
            s.x = f2bf(v.x); s.y = f2bf(v.y); s.z = f2bf(v.z); s.w = f2bf(v.w);
        } else {
            s.x = s.y = s.z = s.w = 0;
        }
        *(ushort4*)(wb + i4) = s;
    } else {
        int idx = (blk - 15360) * 256 + tid;   // < 25600
        wqb[idx] = f2bf(wq[idx]);
        wkb[idx] = f2bf(wk[idx]);
        wvb[idx] = f2bf(wv[idx]);
        int f = idx / E_, e = idx - f * E_;
        wtb[idx] = f2bf(btw[(size_t)e * E_ + f]);
    }
}

// ---------------------------------------------------------------------------
// K1 v3 (verified): cl = (x*std+mean) @ mat via MFMA bf16x3 (hi/lo split).
// ---------------------------------------------------------------------------
__global__ __launch_bounds__(256) void k_cl3(const float* __restrict__ x,
                                             const float* __restrict__ stdv,
                                             const float* __restrict__ meanv,
                                             const float* __restrict__ mat,
                                             float* __restrict__ cl) {
    __shared__ __align__(16) float t[32 * 64];   // 8 KB, XOR-swizzled chunks
    int bx = blockIdx.x, by = blockIdx.y;
    int tid = threadIdx.x, wid = tid >> 6, lane = tid & 63;
    int l32 = lane & 31, hi = lane >> 5;

    #pragma unroll
    for (int s = 0; s < 2; ++s) {
        int u = s * 256 + tid;            // chunk id, 512 total
        int row = u >> 4, c = u & 15;
        int k = c * 4;
        float4 xv = *(const float4*)(x + (size_t)(bx * 32 + row) * 64 + k);
        float4 sv = *(const float4*)(stdv + k);
        float4 mv = *(const float4*)(meanv + k);
        float4 tv;
        tv.x = xv.x * sv.x + mv.x;
        tv.y = xv.y * sv.y + mv.y;
        tv.z = xv.z * sv.z + mv.z;
        tv.w = xv.w * sv.w + mv.w;
        *(float4*)(t + row * 64 + ((c ^ (row & 7)) << 2)) = tv;
    }

    if (by == 0) {
        for (int idx = tid; idx < 32 * PAD_; idx += 256) {
            int row = idx / PAD_, jj = idx - row * PAD_;
            size_t base = (size_t)(bx * 32 + row) * D_TRF;
            cl[base + jj] = 0.f;
            cl[base + (D_TRF - PAD_) + jj] = 0.f;
        }
    }
    __syncthreads();

    int j = by * 128 + wid * 32 + l32;
    bool jok = j < D_CL;

    floatx16 acc = {0.f, 0.f, 0.f, 0.f, 0.f, 0.f, 0.f, 0.f,
                    0.f, 0.f, 0.f, 0.f, 0.f, 0.f, 0.f, 0.f};
    #pragma unroll
    for (int e0i = 0; e0i < 4; ++e0i) {
        int e0 = e0i * 16;
        int c0 = (e0 >> 2) + hi * 2;
        float4 a0 = *(const float4*)(t + l32 * 64 + ((c0 ^ (l32 & 7)) << 2));
        float4 a1 = *(const float4*)(t + l32 * 64 + (((c0 + 1) ^ (l32 & 7)) << 2));
        float av[8] = {a0.x, a0.y, a0.z, a0.w, a1.x, a1.y, a1.z, a1.w};
        short8 ahi, alo;
        #pragma unroll
        for (int q = 0; q < 8; ++q) {
            unsigned short h = f2bf(av[q]);
            ahi[q] = (short)h;
            alo[q] = (short)f2bf(av[q] - bf2f(h));
        }
        float bv[8];
        #pragma unroll
        for (int kk = 0; kk < 8; ++kk) {
            int k = e0 + hi * 8 + kk;
            bv[kk] = jok ? mat[(size_t)k * D_CL + j] : 0.f;
        }
        short8 bhi, blo;
        #pragma unroll
        for (int q = 0; q < 8; ++q) {
            unsigned short h = f2bf(bv[q]);
            bhi[q] = (short)h;
            blo[q] = (short)f2bf(bv[q] - bf2f(h));
        }
        acc = __builtin_amdgcn_mfma_f32_32x32x16_bf16(ahi, bhi, acc, 0, 0, 0);
        acc = __builtin_amdgcn_mfma_f32_32x32x16_bf16(ahi, blo, acc, 0, 0, 0);
        acc = __builtin_amdgcn_mfma_f32_32x32x16_bf16(alo, bhi, acc, 0, 0, 0);
    }

    if (jok) {
        #pragma unroll
        for (int r = 0; r < 16; ++r) {
            int p = (r & 3) + 8 * (r >> 2) + 4 * hi;
            cl[(size_t)(bx * 32 + p) * D_TRF + PAD_ + j] = acc[r];
        }
    }
}

// ---------------------------------------------------------------------------
// K3456 v3 (verified): fused LN + QKV + attention + BT, one block per b,
// 8 waves. LDS 68096 B -> 2 blocks/CU.
// ---------------------------------------------------------------------------
__global__ __launch_bounds__(512) void k_qab(const float* __restrict__ cl,
                                             const float* __restrict__ ln_g,
                                             const float* __restrict__ ln_b,
                                             const unsigned short* __restrict__ wqb,
                                             const unsigned short* __restrict__ wkb,
                                             const unsigned short* __restrict__ wvb,
                                             const unsigned short* __restrict__ wtb,
                                             const float* __restrict__ bq,
                                             const float* __restrict__ bk,
                                             const float* __restrict__ bv,
                                             const float* __restrict__ bt_b,
                                             const float* __restrict__ bt_gain,
                                             const float* __restrict__ bt_bias,
                                             const float* __restrict__ sup_g,
                                             const float* __restrict__ sup_b,
                                             unsigned short* __restrict__ yb) {
    __shared__ __align__(16) char smem[68096];
    float*          clh  = (float*)smem;                              // [32][160] cl -> h
    unsigned short* Qlds = (unsigned short*)(smem + 20480);           // [32][168]
    unsigned short* Klds = Qlds + 32 * 168;                           // [32][168]
    unsigned short* Vtl  = (unsigned short*)(smem + 41984);           // [160][40]
    unsigned short* Satt = (unsigned short*)(smem + 54784);           // [32][40]
    unsigned short* xnl  = (unsigned short*)(smem + 57344);           // [32][168] -> x2

    int b = blockIdx.x;
    int tid = threadIdx.x, wid = tid >> 6, lane = tid & 63;
    int l32 = lane & 31, hi = lane >> 5;

    const float* clg = cl + (size_t)b * D_TRF;
    #pragma unroll
    for (int it = 0; it < 3; ++it) {
        int u = it * 512 + tid;
        if (u < 1280)
            load_lds16(clg + u * 4, (char*)clh + (size_t)u * 16);
    }
    __syncthreads();   // drains vmcnt: cl staged

    {
        float s = 0.f, s2 = 0.f;
        #pragma unroll
        for (int it = 0; it < 10; ++it) {
            float v = clh[it * 512 + tid];
            s += v; s2 += v * v;
        }
        #pragma unroll
        for (int off = 32; off; off >>= 1) {
            s  += __shfl_down(s, off);
            s2 += __shfl_down(s2, off);
        }
        float* red = (float*)Qlds;   // scratch before Q is written
        if (lane == 0) { red[wid] = s; red[8 + wid] = s2; }
        __syncthreads();
        if (tid == 0) {
            float S = 0.f, S2 = 0.f;
            #pragma unroll
            for (int i = 0; i < 8; ++i) { S += red[i]; S2 += red[8 + i]; }
            float mu = S / (float)D_TRF;
            float var = S2 / (float)D_TRF - mu * mu;
            red[16] = mu; red[17] = rsqrtf(var + 1e-5f);
        }
        __syncthreads();
        float mu = red[16], rs = red[17];
        #pragma unroll
        for (int it = 0; it < 10; ++it) {
            int idx = it * 512 + tid;
            int p = idx / 160, e = idx - p * 160;
            xnl[p * 168 + e] = f2bf((clh[idx] - mu) * rs * ln_g[idx] + ln_b[idx]);
        }
    }
    __syncthreads();   // xnl ready; Qlds scratch reads done

    for (int tc = wid; tc < 15; tc += 8) {
        int mat = tc / 5, f0 = (tc - mat * 5) * 32;
        const unsigned short* wsrc = (mat == 0) ? wqb : (mat == 1) ? wkb : wvb;
        const float* bias          = (mat == 0) ? bq  : (mat == 1) ? bk  : bv;
        floatx16 acc = {0.f, 0.f, 0.f, 0.f, 0.f, 0.f, 0.f, 0.f,
                        0.f, 0.f, 0.f, 0.f, 0.f, 0.f, 0.f, 0.f};
        #pragma unroll
        for (int kc = 0; kc < 10; ++kc) {
            int e0 = kc * 16;
            short8 af = *(const short8*)(xnl + l32 * 168 + e0 + hi * 8);
            short8 bf = *(const short8*)(wsrc + (size_t)(f0 + l32) * E_ + e0 + hi * 8);
            acc = __builtin_amdgcn_mfma_f32_32x32x16_bf16(af, bf, acc, 0, 0, 0);
        }
        int f = f0 + l32;
        float bb = bias[f];
        if (mat == 0) {
            #pragma unroll
            for (int r = 0; r < 16; ++r) {
                int p = (r & 3) + 8 * (r >> 2) + 4 * hi;
                Qlds[p * 168 + f] = f2bf(acc[r] + bb);
            }
        } else if (mat == 1) {
            #pragma unroll
            for (int r = 0; r < 16; ++r) {
                int p = (r & 3) + 8 * (r >> 2) + 4 * hi;
                Klds[p * 168 + f] = f2bf(acc[r] + bb);
            }
        } else {
            #pragma unroll
            for (int r = 0; r < 16; ++r) {
                int p = (r & 3) + 8 * (r >> 2) + 4 * hi;
                Vtl[f * 40 + p] = f2bf(acc[r] + bb);   // transposed: [e][q]
            }
        }
    }
    __syncthreads();

    if (wid == 0) {
        floatx16 S = {0.f, 0.f, 0.f, 0.f, 0.f, 0.f, 0.f, 0.f,
                      0.f, 0.f, 0.f, 0.f, 0.f, 0.f, 0.f, 0.f};
        #pragma unroll
        for (int kc = 0; kc < 10; ++kc) {
            int e0 = kc * 16;
            short8 aq = *(const short8*)(Qlds + l32 * 168 + e0 + hi * 8);
            short8 bk2 = *(const short8*)(Klds + l32 * 168 + e0 + hi * 8);
            S = __builtin_amdgcn_mfma_f32_32x32x16_bf16(aq, bk2, S, 0, 0, 0);
        }
        float mx = -1e30f;
        #pragma unroll
        for (int r = 0; r < 16; ++r) { S[r] *= INV_SCALE; mx = fmaxf(mx, S[r]); }
        mx = fmaxf(mx, __shfl_xor(mx, 32));
        float ex[16];
        float sum = 0.f;
        #pragma unroll
        for (int r = 0; r < 16; ++r) { ex[r] = __expf(S[r] - mx); sum += ex[r]; }
        sum += __shfl_xor(sum, 32);
        float inv = 1.f / sum;
        #pragma unroll
        for (int r = 0; r < 16; ++r) {
            int p = (r & 3) + 8 * (r >> 2) + 4 * hi;
            Satt[p * 40 + l32] = f2bf(ex[r] * inv);
        }
    }
    __syncthreads();   // att ready; Q/K dead

    short8 a0 = *(const short8*)(Satt + l32 * 40 + hi * 8);
    short8 a1 = *(const short8*)(Satt + l32 * 40 + 16 + hi * 8);
    float gg = bt_gain[0], bb2 = bt_bias[0];
    if (wid < 5) {
        int e0 = wid * 32;
        short8 b0 = *(const short8*)(Vtl + (e0 + l32) * 40 + hi * 8);
        short8 b1 = *(const short8*)(Vtl + (e0 + l32) * 40 + 16 + hi * 8);
        floatx16 acc = {0.f, 0.f, 0.f, 0.f, 0.f, 0.f, 0.f, 0.f,
                        0.f, 0.f, 0.f, 0.f, 0.f, 0.f, 0.f, 0.f};
        acc = __builtin_amdgcn_mfma_f32_32x32x16_bf16(a0, b0, acc, 0, 0, 0);
        acc = __builtin_amdgcn_mfma_f32_32x32x16_bf16(a1, b1, acc, 0, 0, 0);
        #pragma unroll
        for (int r = 0; r < 16; ++r) {
            int p = (r & 3) + 8 * (r >> 2) + 4 * hi;
            int e = e0 + l32;
            float hv = acc[r] + clh[p * E_ + e];   // read cl, then overwrite as h
            clh[p * E_ + e] = hv;
            xnl[p * 168 + e] = f2bf(hv * gg + bb2);   // x2
        }
    }
    __syncthreads();   // h, x2 ready

    if (wid < 5) {
        int f0 = wid * 32;
        floatx16 acc = {0.f, 0.f, 0.f, 0.f, 0.f, 0.f, 0.f, 0.f,
                        0.f, 0.f, 0.f, 0.f, 0.f, 0.f, 0.f, 0.f};
        #pragma unroll
        for (int kc = 0; kc < 10; ++kc) {
            int e0 = kc * 16;
            short8 af = *(const short8*)(xnl + l32 * 168 + e0 + hi * 8);
            short8 bf = *(const short8*)(wtb + (size_t)(f0 + l32) * E_ + e0 + hi * 8);
            acc = __builtin_amdgcn_mfma_f32_32x32x16_bf16(af, bf, acc, 0, 0, 0);
        }
        int f = f0 + l32;
        float bb = bt_b[f];
        #pragma unroll
        for (int r = 0; r < 16; ++r) {
            int p = (r & 3) + 8 * (r >> 2) + 4 * hi;
            int i = p * E_ + f;
            float o = acc[r] + bb;
            float sig = 1.f / (1.f + __expf(-sup_b[i] * o));
            float y = (sup_g[i] + sig * (1.f - sup_g[i])) * o + clh[p * E_ + f];
            yb[((size_t)b * 32 + p) * E_ + f] = f2bf(y);
        }
    }
}

// ---------------------------------------------------------------------------
// K7: head GEMM v10 (PROVEN, 27.4 us) — m97 template, wb bf16,
// global_load_lds both operands, counted vmcnt(7), 2 blocks/CU.
// Five restructure attempts (m-split, reg-stage, depth-3, atomics, f32-B)
// all regressed; this is the empirical optimum for this shape.
// ---------------------------------------------------------------------------
__global__ __launch_bounds__(256, 2) void k_lin10(const unsigned short* __restrict__ yb,
                                                  const unsigned short* __restrict__ wb,
                                                  float* __restrict__ pb) {
    __shared__ __align__(16) unsigned short As[2][128 * 64];  // 2 x 16 KB
    __shared__ __align__(16) unsigned short Bs[2][96 * 64];   // 2 x 12 KB

    int bid = blockIdx.x;
    int xcd = bid & 7, j = bid >> 3;
    int nt = xcd * 4 + (j & 3);          // 0..31  (96-col tiles)
    int mt = (j >> 2) & 3;               // 0..3   (128-row tiles)
    int sp = j >> 4;                     // 0..3   (split-K, 1280 each)

    int tid = threadIdx.x, wid = tid >> 6, lane = tid & 63;
    int l16 = lane & 15, quad = lane >> 4;
    int wr = wid >> 1, wc = wid & 1;     // 2x2 wave grid

    const size_t aRow0 = (size_t)(mt * 128) * D_TRF;
    const size_t bRow0 = (size_t)(nt * 96) * D_TRF;
    const int k0 = sp * 1280;

    floatx4 acc[4][3];
    #pragma unroll
    for (int fi = 0; fi < 4; ++fi)
        #pragma unroll
        for (int fj = 0; fj < 3; ++fj) acc[fi][fj] = (floatx4){0.f, 0.f, 0.f, 0.f};

    int aOff[4][2], bOff[3][2];
    #pragma unroll
    for (int fi = 0; fi < 4; ++fi) {
        int row = wr * 64 + fi * 16 + l16;
        #pragma unroll
        for (int kk = 0; kk < 2; ++kk)
            aOff[fi][kk] = row * 64 + (((quad + kk * 4) ^ (row & 7)) * 8);
    }
    #pragma unroll
    for (int fj = 0; fj < 3; ++fj) {
        int row = wc * 48 + fj * 16 + l16;
        #pragma unroll
        for (int kk = 0; kk < 2; ++kk)
            bOff[fj][kk] = row * 64 + (((quad + kk * 4) ^ (row & 7)) * 8);
    }

#define STAGE10(buf, t)                                                         \
    do {                                                                        \
        int kh_ = k0 + (t) * 64;                                                \
        _Pragma("unroll")                                                       \
        for (int i_ = 0; i_ < 4; ++i_) {                                        \
            int u_ = i_ * 256 + tid;                                            \
            int row_ = u_ >> 3, c_ = u_ & 7;                                    \
            load_lds16(yb + aRow0 + (size_t)row_ * D_TRF + kh_ +                \
                           ((c_ ^ (row_ & 7)) * 8),                             \
                       (char*)(&As[buf][0]) + (size_t)u_ * 16);                 \
        }                                                                       \
        _Pragma("unroll")                                                       \
        for (int i_ = 0; i_ < 3; ++i_) {                                        \
            int u_ = i_ * 256 + tid;                                            \
            int row_ = u_ >> 3, c_ = u_ & 7;                                    \
            load_lds16(wb + bRow0 + (size_t)row_ * D_TRF + kh_ +                \
                           ((c_ ^ (row_ & 7)) * 8),                             \
                       (char*)(&Bs[buf][0]) + (size_t)u_ * 16);                 \
        }                                                                       \
    } while (0)

    STAGE10(0, 0);                            // 7 in flight; no wait here

    for (int t = 0; t < 20; ++t) {
        int cur = t & 1;
        if (t < 19) {
            STAGE10(cur ^ 1, t + 1);          // -> 14 in flight
            asm volatile("s_waitcnt vmcnt(7)" ::: "memory");   // tile t landed
        } else {
            asm volatile("s_waitcnt vmcnt(0)" ::: "memory");   // last tile
        }
        __builtin_amdgcn_s_barrier();         // raw: does NOT drain vmcnt

        const unsigned short* Ab = &As[cur][0];
        const unsigned short* Bb = &Bs[cur][0];
        short8 af[4][2], bfr[3][2];
        #pragma unroll
        for (int fi = 0; fi < 4; ++fi)
            #pragma unroll
            for (int kk = 0; kk < 2; ++kk)
                af[fi][kk] = *(const short8*)(Ab + aOff[fi][kk]);
        #pragma unroll
        for (int fj = 0; fj < 3; ++fj)
            #pragma unroll
            for (int kk = 0; kk < 2; ++kk)
                bfr[fj][kk] = *(const short8*)(Bb + bOff[fj][kk]);

        #pragma unroll
        for (int kk = 0; kk < 2; ++kk)
            #pragma unroll
            for (int fi = 0; fi < 4; ++fi)
                #pragma unroll
                for (int fj = 0; fj < 3; ++fj)
                    acc[fi][fj] = __builtin_amdgcn_mfma_f32_16x16x32_bf16(
                        af[fi][kk], bfr[fj][kk], acc[fi][fj], 0, 0, 0);

        asm volatile("s_waitcnt lgkmcnt(0)" ::: "memory");  // all ds_reads done
        __builtin_amdgcn_s_barrier();         // guards buf overwrite next iter
    }
#undef STAGE10

    #pragma unroll
    for (int fi = 0; fi < 4; ++fi) {
        int row = mt * 128 + wr * 64 + fi * 16 + quad * 4;
        #pragma unroll
        for (int fj = 0; fj < 3; ++fj) {
            int col = nt * 96 + wc * 48 + fj * 16 + l16;
            #pragma unroll
            for (int r = 0; r < 4; ++r)
                pb[((size_t)(sp * 512 + row + r)) * 3072 + col] = acc[fi][fj][r];
        }
    }
}

// ---------------------------------------------------------------------------
// K8 v2: reduce 4 split-K partials + bias/gain, float4-vectorized.
// 512 rows x 750 col4 = 384000 threads, exact cover.
// ---------------------------------------------------------------------------
__global__ __launch_bounds__(256) void k_red2(const float* __restrict__ pb,
                                              const float* __restrict__ lin_b,
                                              const float* __restrict__ out_gain,
                                              const float* __restrict__ out_bias,
                                              float* __restrict__ out) {
    int idx = blockIdx.x * 256 + threadIdx.x;   // < 384000
    int row = idx / 750, c4 = idx - row * 750;
    size_t base = (size_t)row * 3072 + c4 * 4;
    const size_t stride = (size_t)512 * 3072;
    float4 s0 = *(const float4*)(pb + base);
    float4 s1 = *(const float4*)(pb + base + stride);
    float4 s2 = *(const float4*)(pb + base + 2 * stride);
    float4 s3 = *(const float4*)(pb + base + 3 * stride);
    float4 lb = *(const float4*)(lin_b + c4 * 4);
    float g = out_gain[0], ob = out_bias[0];
    float4 o;
    o.x = (s0.x + s1.x + s2.x + s3.x + lb.x) * g + ob;
    o.y = (s0.y + s1.y + s2.y + s3.y + lb.y) * g + ob;
    o.z = (s0.z + s1.z + s2.z + s3.z + lb.z) * g + ob;
    o.w = (s0.w + s1.w + s2.w + s3.w + lb.w) * g + ob;
    *(float4*)(out + (size_t)row * D_OUT + c4 * 4) = o;
}

// ---------------------------------------------------------------------------
// Workspace layout (bytes)
// ---------------------------------------------------------------------------
#define SZ_ROWF ((size_t)B_ * D_TRF * 4)           // 10,485,760
#define SZ_ROWB ((size_t)B_ * D_TRF * 2)           // 5,242,880
#define OFF_CL  ((size_t)0)
#define OFF_YB  (OFF_CL + 2 * SZ_ROWF + 4 * SZ_ROWB)   // 41,943,040
#define OFF_WSM (OFF_YB + SZ_ROWB)                 // 4 x 51200 B
#define OFF_WB  (OFF_WSM + (size_t)4 * E_ * E_ * 2)
// end = OFF_WB + 3072*5120*2 = 78,848,000 bytes
// pb (4*512*3072*4 = 25,165,824 B) aliases OFF_CL..: cl is dead once k_qab
// has run, and 25.2 MB < OFF_YB (41.9 MB) -> yb untouched.

extern "C" void kernel_launch(void* const* d_in, const int* in_sizes, int n_in,
                              void* d_out, int out_size, void* d_ws, size_t ws_size,
                              hipStream_t stream) {
    const float* x        = (const float*)d_in[0];
    const float* stdv     = (const float*)d_in[1];
    const float* meanv    = (const float*)d_in[2];
    const float* mat      = (const float*)d_in[3];
    const float* ln_g     = (const float*)d_in[4];
    const float* ln_b     = (const float*)d_in[5];
    const float* wq       = (const float*)d_in[6];
    const float* bq       = (const float*)d_in[7];
    const float* wk       = (const float*)d_in[8];
    const float* bk       = (const float*)d_in[9];
    const float* wv       = (const float*)d_in[10];
    const float* bv       = (const float*)d_in[11];
    const float* bt_w     = (const float*)d_in[12];
    const float* bt_b     = (const float*)d_in[13];
    const float* bt_gain  = (const float*)d_in[14];
    const float* bt_bias  = (const float*)d_in[15];
    const float* sup_g    = (const float*)d_in[16];
    const float* sup_b    = (const float*)d_in[17];
    const float* lin_w    = (const float*)d_in[18];
    const float* lin_b    = (const float*)d_in[19];
    const float* out_gain = (const float*)d_in[20];
    const float* out_bias = (const float*)d_in[21];

    char* ws = (char*)d_ws;
    float* cl = (float*)(ws + OFF_CL);
    unsigned short* yb  = (unsigned short*)(ws + OFF_YB);
    unsigned short* wqb = (unsigned short*)(ws + OFF_WSM);
    unsigned short* wkb = wqb + E_ * E_;
    unsigned short* wvb = wkb + E_ * E_;
    unsigned short* wtb = wvb + E_ * E_;
    unsigned short* wb  = (unsigned short*)(ws + OFF_WB);
    float* pb = (float*)(ws + OFF_CL);   // aliases cl (dead by k_lin10)
    float* out = (float*)d_out;

    k_castw2<<<15460, 256, 0, stream>>>(lin_w, wb, wq, wk, wv, bt_w,
                                        wqb, wkb, wvb, wtb);
    k_cl3<<<dim3(16, 40), 256, 0, stream>>>(x, stdv, meanv, mat, cl);
    k_qab<<<512, 512, 0, stream>>>(cl, ln_g, ln_b, wqb, wkb, wvb, wtb,
                                   bq, bk, bv, bt_b, bt_gain, bt_bias,
                                   sup_g, sup_b, yb);
    k_lin10<<<512, 256, 0, stream>>>(yb, wb, pb);
    k_red2<<<1500, 256, 0, stream>>>(pb, lin_b, out_gain, out_bias, out);
}

// Round 16
// 186.473 us; speedup vs baseline: 1.1386x; 1.0208x over previous
//
#include <hip/hip_runtime.h>

// Problem constants
#define B_    512
#define D_TRF 5120
#define P_    32
#define E_    160
#define D_OUT 3000
#define PAD_  61
#define D_CL  4998
#define INV_SCALE 0.07905694150420949f   // 1/sqrt(160)
#define N_PAD 3072          // lin_w rows padded (32 tiles of 96)

typedef __attribute__((ext_vector_type(4))) float floatx4;
typedef __attribute__((ext_vector_type(16))) float floatx16;
typedef __attribute__((ext_vector_type(8))) short short8;

static __device__ __forceinline__ unsigned short f2bf(float f) {
    unsigned int u = __float_as_uint(f);
    unsigned int r = (u + 0x7fffu + ((u >> 16) & 1u)) >> 16;
    return (unsigned short)r;
}
static __device__ __forceinline__ float bf2f(unsigned short u) {
    return __uint_as_float(((unsigned int)u) << 16);
}
static __device__ __forceinline__ void load_lds16(const void* g, void* lds) {
    __builtin_amdgcn_global_load_lds(
        (const __attribute__((address_space(1))) unsigned int*)g,
        (__attribute__((address_space(3))) unsigned int*)lds, 16, 0, 0);
}

// ---------------------------------------------------------------------------
// K_PREP2: cl3 (MFMA bf16x3) + lin_w/small casts in ONE dispatch.
// Unlike R9's failed fusion (coarse cl blocks spanning the whole kernel),
// cl3's 640 blocks are fine-grained (~3us each) -> the mix behaves like
// concatenation, saving the serial gap + overlap (~6-8us).
//   blocks [0,640):        cl = (x*std+mean) @ mat  (bx=blk&15, by=blk>>4)
//   blocks [640,16000):    lin_w f32 -> wb bf16 [3072,5120] (pads zeroed)
//   blocks [16000,16100):  wq/wk/wv cast + bt_w transpose-cast
// ---------------------------------------------------------------------------
__global__ __launch_bounds__(256) void k_prep2(const float* __restrict__ x,
                                               const float* __restrict__ stdv,
                                               const float* __restrict__ meanv,
                                               const float* __restrict__ mat,
                                               float* __restrict__ cl,
                                               const float* __restrict__ w,
                                               unsigned short* __restrict__ wb,
                                               const float* __restrict__ wq,
                                               const float* __restrict__ wk,
                                               const float* __restrict__ wv,
                                               const float* __restrict__ btw,
                                               unsigned short* __restrict__ wqb,
                                               unsigned short* __restrict__ wkb,
                                               unsigned short* __restrict__ wvb,
                                               unsigned short* __restrict__ wtb) {
    __shared__ __align__(16) float t[32 * 64];   // 8 KB (cl segment only)
    int blk = blockIdx.x, tid = threadIdx.x;

    if (blk < 640) {
        // ---- cl3: MFMA bf16x3 tile (verified logic, unchanged) ----
        int bx = blk & 15, by = blk >> 4;
        int wid = tid >> 6, lane = tid & 63;
        int l32 = lane & 31, hi = lane >> 5;

        #pragma unroll
        for (int s = 0; s < 2; ++s) {
            int u = s * 256 + tid;            // chunk id, 512 total
            int row = u >> 4, c = u & 15;
            int k = c * 4;
            float4 xv = *(const float4*)(x + (size_t)(bx * 32 + row) * 64 + k);
            float4 sv = *(const float4*)(stdv + k);
            float4 mv = *(const float4*)(meanv + k);
            float4 tv;
            tv.x = xv.x * sv.x + mv.x;
            tv.y = xv.y * sv.y + mv.y;
            tv.z = xv.z * sv.z + mv.z;
            tv.w = xv.w * sv.w + mv.w;
            *(float4*)(t + row * 64 + ((c ^ (row & 7)) << 2)) = tv;
        }

        if (by == 0) {
            for (int idx = tid; idx < 32 * PAD_; idx += 256) {
                int row = idx / PAD_, jj = idx - row * PAD_;
                size_t base = (size_t)(bx * 32 + row) * D_TRF;
                cl[base + jj] = 0.f;
                cl[base + (D_TRF - PAD_) + jj] = 0.f;
            }
        }
        __syncthreads();

        int j = by * 128 + wid * 32 + l32;
        bool jok = j < D_CL;

        floatx16 acc = {0.f, 0.f, 0.f, 0.f, 0.f, 0.f, 0.f, 0.f,
                        0.f, 0.f, 0.f, 0.f, 0.f, 0.f, 0.f, 0.f};
        #pragma unroll
        for (int e0i = 0; e0i < 4; ++e0i) {
            int e0 = e0i * 16;
            int c0 = (e0 >> 2) + hi * 2;
            float4 a0 = *(const float4*)(t + l32 * 64 + ((c0 ^ (l32 & 7)) << 2));
            float4 a1 = *(const float4*)(t + l32 * 64 + (((c0 + 1) ^ (l32 & 7)) << 2));
            float av[8] = {a0.x, a0.y, a0.z, a0.w, a1.x, a1.y, a1.z, a1.w};
            short8 ahi, alo;
            #pragma unroll
            for (int q = 0; q < 8; ++q) {
                unsigned short h = f2bf(av[q]);
                ahi[q] = (short)h;
                alo[q] = (short)f2bf(av[q] - bf2f(h));
            }
            float bv[8];
            #pragma unroll
            for (int kk = 0; kk < 8; ++kk) {
                int k = e0 + hi * 8 + kk;
                bv[kk] = jok ? mat[(size_t)k * D_CL + j] : 0.f;
            }
            short8 bhi, blo;
            #pragma unroll
            for (int q = 0; q < 8; ++q) {
                unsigned short h = f2bf(bv[q]);
                bhi[q] = (short)h;
                blo[q] = (short)f2bf(bv[q] - bf2f(h));
            }
            acc = __builtin_amdgcn_mfma_f32_32x32x16_bf16(ahi, bhi, acc, 0, 0, 0);
            acc = __builtin_amdgcn_mfma_f32_32x32x16_bf16(ahi, blo, acc, 0, 0, 0);
            acc = __builtin_amdgcn_mfma_f32_32x32x16_bf16(alo, bhi, acc, 0, 0, 0);
        }

        if (jok) {
            #pragma unroll
            for (int r = 0; r < 16; ++r) {
                int p = (r & 3) + 8 * (r >> 2) + 4 * hi;
                cl[(size_t)(bx * 32 + p) * D_TRF + PAD_ + j] = acc[r];
            }
        }
    } else if (blk < 16000) {
        // ---- lin_w cast (pad rows zeroed) ----
        size_t i4 = ((size_t)(blk - 640) * 256 + tid) * 4;
        size_t o = i4 / D_TRF;
        ushort4 s;
        if (o < D_OUT) {
            float4 v = *(const float4*)(w + i4);
            s.x = f2bf(v.x); s.y = f2bf(v.y); s.z = f2bf(v.z); s.w = f2bf(v.w);
        } else {
            s.x = s.y = s.z = s.w = 0;
        }
        *(ushort4*)(wb + i4) = s;
    } else {
        // ---- small-weight casts ----
        int idx = (blk - 16000) * 256 + tid;   // < 25600
        wqb[idx] = f2bf(wq[idx]);
        wkb[idx] = f2bf(wk[idx]);
        wvb[idx] = f2bf(wv[idx]);
        int f = idx / E_, e = idx - f * E_;
        wtb[idx] = f2bf(btw[(size_t)e * E_ + f]);
    }
}

// ---------------------------------------------------------------------------
// K3456 v3 (verified): fused LN + QKV + attention + BT, one block per b,
// 8 waves. LDS 68096 B -> 2 blocks/CU.
// ---------------------------------------------------------------------------
__global__ __launch_bounds__(512) void k_qab(const float* __restrict__ cl,
                                             const float* __restrict__ ln_g,
                                             const float* __restrict__ ln_b,
                                             const unsigned short* __restrict__ wqb,
                                             const unsigned short* __restrict__ wkb,
                                             const unsigned short* __restrict__ wvb,
                                             const unsigned short* __restrict__ wtb,
                                             const float* __restrict__ bq,
                                             const float* __restrict__ bk,
                                             const float* __restrict__ bv,
                                             const float* __restrict__ bt_b,
                                             const float* __restrict__ bt_gain,
                                             const float* __restrict__ bt_bias,
                                             const float* __restrict__ sup_g,
                                             const float* __restrict__ sup_b,
                                             unsigned short* __restrict__ yb) {
    __shared__ __align__(16) char smem[68096];
    float*          clh  = (float*)smem;                              // [32][160] cl -> h
    unsigned short* Qlds = (unsigned short*)(smem + 20480);           // [32][168]
    unsigned short* Klds = Qlds + 32 * 168;                           // [32][168]
    unsigned short* Vtl  = (unsigned short*)(smem + 41984);           // [160][40]
    unsigned short* Satt = (unsigned short*)(smem + 54784);           // [32][40]
    unsigned short* xnl  = (unsigned short*)(smem + 57344);           // [32][168] -> x2

    int b = blockIdx.x;
    int tid = threadIdx.x, wid = tid >> 6, lane = tid & 63;
    int l32 = lane & 31, hi = lane >> 5;

    const float* clg = cl + (size_t)b * D_TRF;
    #pragma unroll
    for (int it = 0; it < 3; ++it) {
        int u = it * 512 + tid;
        if (u < 1280)
            load_lds16(clg + u * 4, (char*)clh + (size_t)u * 16);
    }
    __syncthreads();   // drains vmcnt: cl staged

    {
        float s = 0.f, s2 = 0.f;
        #pragma unroll
        for (int it = 0; it < 10; ++it) {
            float v = clh[it * 512 + tid];
            s += v; s2 += v * v;
        }
        #pragma unroll
        for (int off = 32; off; off >>= 1) {
            s  += __shfl_down(s, off);
            s2 += __shfl_down(s2, off);
        }
        float* red = (float*)Qlds;   // scratch before Q is written
        if (lane == 0) { red[wid] = s; red[8 + wid] = s2; }
        __syncthreads();
        if (tid == 0) {
            float S = 0.f, S2 = 0.f;
            #pragma unroll
            for (int i = 0; i < 8; ++i) { S += red[i]; S2 += red[8 + i]; }
            float mu = S / (float)D_TRF;
            float var = S2 / (float)D_TRF - mu * mu;
            red[16] = mu; red[17] = rsqrtf(var + 1e-5f);
        }
        __syncthreads();
        float mu = red[16], rs = red[17];
        #pragma unroll
        for (int it = 0; it < 10; ++it) {
            int idx = it * 512 + tid;
            int p = idx / 160, e = idx - p * 160;
            xnl[p * 168 + e] = f2bf((clh[idx] - mu) * rs * ln_g[idx] + ln_b[idx]);
        }
    }
    __syncthreads();   // xnl ready; Qlds scratch reads done

    for (int tc = wid; tc < 15; tc += 8) {
        int mat = tc / 5, f0 = (tc - mat * 5) * 32;
        const unsigned short* wsrc = (mat == 0) ? wqb : (mat == 1) ? wkb : wvb;
        const float* bias          = (mat == 0) ? bq  : (mat == 1) ? bk  : bv;
        floatx16 acc = {0.f, 0.f, 0.f, 0.f, 0.f, 0.f, 0.f, 0.f,
                        0.f, 0.f, 0.f, 0.f, 0.f, 0.f, 0.f, 0.f};
        #pragma unroll
        for (int kc = 0; kc < 10; ++kc) {
            int e0 = kc * 16;
            short8 af = *(const short8*)(xnl + l32 * 168 + e0 + hi * 8);
            short8 bf = *(const short8*)(wsrc + (size_t)(f0 + l32) * E_ + e0 + hi * 8);
            acc = __builtin_amdgcn_mfma_f32_32x32x16_bf16(af, bf, acc, 0, 0, 0);
        }
        int f = f0 + l32;
        float bb = bias[f];
        if (mat == 0) {
            #pragma unroll
            for (int r = 0; r < 16; ++r) {
                int p = (r & 3) + 8 * (r >> 2) + 4 * hi;
                Qlds[p * 168 + f] = f2bf(acc[r] + bb);
            }
        } else if (mat == 1) {
            #pragma unroll
            for (int r = 0; r < 16; ++r) {
                int p = (r & 3) + 8 * (r >> 2) + 4 * hi;
                Klds[p * 168 + f] = f2bf(acc[r] + bb);
            }
        } else {
            #pragma unroll
            for (int r = 0; r < 16; ++r) {
                int p = (r & 3) + 8 * (r >> 2) + 4 * hi;
                Vtl[f * 40 + p] = f2bf(acc[r] + bb);   // transposed: [e][q]
            }
        }
    }
    __syncthreads();

    if (wid == 0) {
        floatx16 S = {0.f, 0.f, 0.f, 0.f, 0.f, 0.f, 0.f, 0.f,
                      0.f, 0.f, 0.f, 0.f, 0.f, 0.f, 0.f, 0.f};
        #pragma unroll
        for (int kc = 0; kc < 10; ++kc) {
            int e0 = kc * 16;
            short8 aq = *(const short8*)(Qlds + l32 * 168 + e0 + hi * 8);
            short8 bk2 = *(const short8*)(Klds + l32 * 168 + e0 + hi * 8);
            S = __builtin_amdgcn_mfma_f32_32x32x16_bf16(aq, bk2, S, 0, 0, 0);
        }
        float mx = -1e30f;
        #pragma unroll
        for (int r = 0; r < 16; ++r) { S[r] *= INV_SCALE; mx = fmaxf(mx, S[r]); }
        mx = fmaxf(mx, __shfl_xor(mx, 32));
        float ex[16];
        float sum = 0.f;
        #pragma unroll
        for (int r = 0; r < 16; ++r) { ex[r] = __expf(S[r] - mx); sum += ex[r]; }
        sum += __shfl_xor(sum, 32);
        float inv = 1.f / sum;
        #pragma unroll
        for (int r = 0; r < 16; ++r) {
            int p = (r & 3) + 8 * (r >> 2) + 4 * hi;
            Satt[p * 40 + l32] = f2bf(ex[r] * inv);
        }
    }
    __syncthreads();   // att ready; Q/K dead

    short8 a0 = *(const short8*)(Satt + l32 * 40 + hi * 8);
    short8 a1 = *(const short8*)(Satt + l32 * 40 + 16 + hi * 8);
    float gg = bt_gain[0], bb2 = bt_bias[0];
    if (wid < 5) {
        int e0 = wid * 32;
        short8 b0 = *(const short8*)(Vtl + (e0 + l32) * 40 + hi * 8);
        short8 b1 = *(const short8*)(Vtl + (e0 + l32) * 40 + 16 + hi * 8);
        floatx16 acc = {0.f, 0.f, 0.f, 0.f, 0.f, 0.f, 0.f, 0.f,
                        0.f, 0.f, 0.f, 0.f, 0.f, 0.f, 0.f, 0.f};
        acc = __builtin_amdgcn_mfma_f32_32x32x16_bf16(a0, b0, acc, 0, 0, 0);
        acc = __builtin_amdgcn_mfma_f32_32x32x16_bf16(a1, b1, acc, 0, 0, 0);
        #pragma unroll
        for (int r = 0; r < 16; ++r) {
            int p = (r & 3) + 8 * (r >> 2) + 4 * hi;
            int e = e0 + l32;
            float hv = acc[r] + clh[p * E_ + e];   // read cl, then overwrite as h
            clh[p * E_ + e] = hv;
            xnl[p * 168 + e] = f2bf(hv * gg + bb2);   // x2
        }
    }
    __syncthreads();   // h, x2 ready

    if (wid < 5) {
        int f0 = wid * 32;
        floatx16 acc = {0.f, 0.f, 0.f, 0.f, 0.f, 0.f, 0.f, 0.f,
                        0.f, 0.f, 0.f, 0.f, 0.f, 0.f, 0.f, 0.f};
        #pragma unroll
        for (int kc = 0; kc < 10; ++kc) {
            int e0 = kc * 16;
            short8 af = *(const short8*)(xnl + l32 * 168 + e0 + hi * 8);
            short8 bf = *(const short8*)(wtb + (size_t)(f0 + l32) * E_ + e0 + hi * 8);
            acc = __builtin_amdgcn_mfma_f32_32x32x16_bf16(af, bf, acc, 0, 0, 0);
        }
        int f = f0 + l32;
        float bb = bt_b[f];
        #pragma unroll
        for (int r = 0; r < 16; ++r) {
            int p = (r & 3) + 8 * (r >> 2) + 4 * hi;
            int i = p * E_ + f;
            float o = acc[r] + bb;
            float sig = 1.f / (1.f + __expf(-sup_b[i] * o));
            float y = (sup_g[i] + sig * (1.f - sup_g[i])) * o + clh[p * E_ + f];
            yb[((size_t)b * 32 + p) * E_ + f] = f2bf(y);
        }
    }
}

// ---------------------------------------------------------------------------
// K7: head GEMM v10 (PROVEN, 27.4 us) — m97 template, wb bf16,
// global_load_lds both operands, counted vmcnt(7), 2 blocks/CU.
// ---------------------------------------------------------------------------
__global__ __launch_bounds__(256, 2) void k_lin10(const unsigned short* __restrict__ yb,
                                                  const unsigned short* __restrict__ wb,
                                                  float* __restrict__ pb) {
    __shared__ __align__(16) unsigned short As[2][128 * 64];  // 2 x 16 KB
    __shared__ __align__(16) unsigned short Bs[2][96 * 64];   // 2 x 12 KB

    int bid = blockIdx.x;
    int xcd = bid & 7, j = bid >> 3;
    int nt = xcd * 4 + (j & 3);          // 0..31  (96-col tiles)
    int mt = (j >> 2) & 3;               // 0..3   (128-row tiles)
    int sp = j >> 4;                     // 0..3   (split-K, 1280 each)

    int tid = threadIdx.x, wid = tid >> 6, lane = tid & 63;
    int l16 = lane & 15, quad = lane >> 4;
    int wr = wid >> 1, wc = wid & 1;     // 2x2 wave grid

    const size_t aRow0 = (size_t)(mt * 128) * D_TRF;
    const size_t bRow0 = (size_t)(nt * 96) * D_TRF;
    const int k0 = sp * 1280;

    floatx4 acc[4][3];
    #pragma unroll
    for (int fi = 0; fi < 4; ++fi)
        #pragma unroll
        for (int fj = 0; fj < 3; ++fj) acc[fi][fj] = (floatx4){0.f, 0.f, 0.f, 0.f};

    int aOff[4][2], bOff[3][2];
    #pragma unroll
    for (int fi = 0; fi < 4; ++fi) {
        int row = wr * 64 + fi * 16 + l16;
        #pragma unroll
        for (int kk = 0; kk < 2; ++kk)
            aOff[fi][kk] = row * 64 + (((quad + kk * 4) ^ (row & 7)) * 8);
    }
    #pragma unroll
    for (int fj = 0; fj < 3; ++fj) {
        int row = wc * 48 + fj * 16 + l16;
        #pragma unroll
        for (int kk = 0; kk < 2; ++kk)
            bOff[fj][kk] = row * 64 + (((quad + kk * 4) ^ (row & 7)) * 8);
    }

#define STAGE10(buf, t)                                                         \
    do {                                                                        \
        int kh_ = k0 + (t) * 64;                                                \
        _Pragma("unroll")                                                       \
        for (int i_ = 0; i_ < 4; ++i_) {                                        \
            int u_ = i_ * 256 + tid;                                            \
            int row_ = u_ >> 3, c_ = u_ & 7;                                    \
            load_lds16(yb + aRow0 + (size_t)row_ * D_TRF + kh_ +                \
                           ((c_ ^ (row_ & 7)) * 8),                             \
                       (char*)(&As[buf][0]) + (size_t)u_ * 16);                 \
        }                                                                       \
        _Pragma("unroll")                                                       \
        for (int i_ = 0; i_ < 3; ++i_) {                                        \
            int u_ = i_ * 256 + tid;                                            \
            int row_ = u_ >> 3, c_ = u_ & 7;                                    \
            load_lds16(wb + bRow0 + (size_t)row_ * D_TRF + kh_ +                \
                           ((c_ ^ (row_ & 7)) * 8),                             \
                       (char*)(&Bs[buf][0]) + (size_t)u_ * 16);                 \
        }                                                                       \
    } while (0)

    STAGE10(0, 0);                            // 7 in flight; no wait here

    for (int t = 0; t < 20; ++t) {
        int cur = t & 1;
        if (t < 19) {
            STAGE10(cur ^ 1, t + 1);          // -> 14 in flight
            asm volatile("s_waitcnt vmcnt(7)" ::: "memory");   // tile t landed
        } else {
            asm volatile("s_waitcnt vmcnt(0)" ::: "memory");   // last tile
        }
        __builtin_amdgcn_s_barrier();         // raw: does NOT drain vmcnt

        const unsigned short* Ab = &As[cur][0];
        const unsigned short* Bb = &Bs[cur][0];
        short8 af[4][2], bfr[3][2];
        #pragma unroll
        for (int fi = 0; fi < 4; ++fi)
            #pragma unroll
            for (int kk = 0; kk < 2; ++kk)
                af[fi][kk] = *(const short8*)(Ab + aOff[fi][kk]);
        #pragma unroll
        for (int fj = 0; fj < 3; ++fj)
            #pragma unroll
            for (int kk = 0; kk < 2; ++kk)
                bfr[fj][kk] = *(const short8*)(Bb + bOff[fj][kk]);

        #pragma unroll
        for (int kk = 0; kk < 2; ++kk)
            #pragma unroll
            for (int fi = 0; fi < 4; ++fi)
                #pragma unroll
                for (int fj = 0; fj < 3; ++fj)
                    acc[fi][fj] = __builtin_amdgcn_mfma_f32_16x16x32_bf16(
                        af[fi][kk], bfr[fj][kk], acc[fi][fj], 0, 0, 0);

        asm volatile("s_waitcnt lgkmcnt(0)" ::: "memory");  // all ds_reads done
        __builtin_amdgcn_s_barrier();         // guards buf overwrite next iter
    }
#undef STAGE10

    #pragma unroll
    for (int fi = 0; fi < 4; ++fi) {
        int row = mt * 128 + wr * 64 + fi * 16 + quad * 4;
        #pragma unroll
        for (int fj = 0; fj < 3; ++fj) {
            int col = nt * 96 + wc * 48 + fj * 16 + l16;
            #pragma unroll
            for (int r = 0; r < 4; ++r)
                pb[((size_t)(sp * 512 + row + r)) * 3072 + col] = acc[fi][fj][r];
        }
    }
}

// ---------------------------------------------------------------------------
// K8 v2: reduce 4 split-K partials + bias/gain, float4-vectorized.
// ---------------------------------------------------------------------------
__global__ __launch_bounds__(256) void k_red2(const float* __restrict__ pb,
                                              const float* __restrict__ lin_b,
                                              const float* __restrict__ out_gain,
                                              const float* __restrict__ out_bias,
                                              float* __restrict__ out) {
    int idx = blockIdx.x * 256 + threadIdx.x;   // < 384000
    int row = idx / 750, c4 = idx - row * 750;
    size_t base = (size_t)row * 3072 + c4 * 4;
    const size_t stride = (size_t)512 * 3072;
    float4 s0 = *(const float4*)(pb + base);
    float4 s1 = *(const float4*)(pb + base + stride);
    float4 s2 = *(const float4*)(pb + base + 2 * stride);
    float4 s3 = *(const float4*)(pb + base + 3 * stride);
    float4 lb = *(const float4*)(lin_b + c4 * 4);
    float g = out_gain[0], ob = out_bias[0];
    float4 o;
    o.x = (s0.x + s1.x + s2.x + s3.x + lb.x) * g + ob;
    o.y = (s0.y + s1.y + s2.y + s3.y + lb.y) * g + ob;
    o.z = (s0.z + s1.z + s2.z + s3.z + lb.z) * g + ob;
    o.w = (s0.w + s1.w + s2.w + s3.w + lb.w) * g + ob;
    *(float4*)(out + (size_t)row * D_OUT + c4 * 4) = o;
}

// ---------------------------------------------------------------------------
// Workspace layout (bytes)
// ---------------------------------------------------------------------------
#define SZ_ROWF ((size_t)B_ * D_TRF * 4)           // 10,485,760
#define SZ_ROWB ((size_t)B_ * D_TRF * 2)           // 5,242,880
#define OFF_CL  ((size_t)0)
#define OFF_YB  (OFF_CL + 2 * SZ_ROWF + 4 * SZ_ROWB)   // 41,943,040
#define OFF_WSM (OFF_YB + SZ_ROWB)                 // 4 x 51200 B
#define OFF_WB  (OFF_WSM + (size_t)4 * E_ * E_ * 2)
// end = OFF_WB + 3072*5120*2 = 78,848,000 bytes
// pb (4*512*3072*4 = 25,165,824 B) aliases OFF_CL..: cl is dead once k_qab
// has run, and 25.2 MB < OFF_YB (41.9 MB) -> yb untouched.

extern "C" void kernel_launch(void* const* d_in, const int* in_sizes, int n_in,
                              void* d_out, int out_size, void* d_ws, size_t ws_size,
                              hipStream_t stream) {
    const float* x        = (const float*)d_in[0];
    const float* stdv     = (const float*)d_in[1];
    const float* meanv    = (const float*)d_in[2];
    const float* mat      = (const float*)d_in[3];
    const float* ln_g     = (const float*)d_in[4];
    const float* ln_b     = (const float*)d_in[5];
    const float* wq       = (const float*)d_in[6];
    const float* bq       = (const float*)d_in[7];
    const float* wk       = (const float*)d_in[8];
    const float* bk       = (const float*)d_in[9];
    const float* wv       = (const float*)d_in[10];
    const float* bv       = (const float*)d_in[11];
    const float* bt_w     = (const float*)d_in[12];
    const float* bt_b     = (const float*)d_in[13];
    const float* bt_gain  = (const float*)d_in[14];
    const float* bt_bias  = (const float*)d_in[15];
    const float* sup_g    = (const float*)d_in[16];
    const float* sup_b    = (const float*)d_in[17];
    const float* lin_w    = (const float*)d_in[18];
    const float* lin_b    = (const float*)d_in[19];
    const float* out_gain = (const float*)d_in[20];
    const float* out_bias = (const float*)d_in[21];

    char* ws = (char*)d_ws;
    float* cl = (float*)(ws + OFF_CL);
    unsigned short* yb  = (unsigned short*)(ws + OFF_YB);
    unsigned short* wqb = (unsigned short*)(ws + OFF_WSM);
    unsigned short* wkb = wqb + E_ * E_;
    unsigned short* wvb = wkb + E_ * E_;
    unsigned short* wtb = wvb + E_ * E_;
    unsigned short* wb  = (unsigned short*)(ws + OFF_WB);
    float* pb = (float*)(ws + OFF_CL);   // aliases cl (dead by k_lin10)
    float* out = (float*)d_out;

    k_prep2<<<16100, 256, 0, stream>>>(x, stdv, meanv, mat, cl, lin_w, wb,
                                       wq, wk, wv, bt_w, wqb, wkb, wvb, wtb);
    k_qab<<<512, 512, 0, stream>>>(cl, ln_g, ln_b, wqb, wkb, wvb, wtb,
                                   bq, bk, bv, bt_b, bt_gain, bt_bias,
                                   sup_g, sup_b, yb);
    k_lin10<<<512, 256, 0, stream>>>(yb, wb, pb);
    k_red2<<<1500, 256, 0, stream>>>(pb, lin_b, out_gain, out_bias, out);
}